// Round 8
// baseline (30320.349 us; speedup 1.0000x reference)
//
#include <hip/hip_runtime.h>

typedef unsigned int u32;
using bf16x8 = __attribute__((ext_vector_type(8))) short;
using f32x4  = __attribute__((ext_vector_type(4))) float;
using f32x2  = __attribute__((ext_vector_type(2))) float;

#define NN 20000
#define EE 320000
#define DH 128
#define DIN 64
#define TSTEPS 20
#define LNEPS 1e-5f
#define NCHUNK 1250   // 20000 / 16-node chunks; 1 persistent block per chunk

// ---------- helpers ----------
__device__ __forceinline__ u32 f2bf(float f) {
    u32 x = __float_as_uint(f);
    return (x + 0x7fffu + ((x >> 16) & 1u)) >> 16;   // RNE to bf16 bits
}
__device__ __forceinline__ float bflo(u32 p) { return __uint_as_float(p << 16); }
__device__ __forceinline__ float bfhi(u32 p) { return __uint_as_float(p & 0xffff0000u); }
__device__ __forceinline__ u32 packbf(float a, float b) { return f2bf(a) | (f2bf(b) << 16); }
__device__ __forceinline__ float wredsum(float v) {
#pragma unroll
    for (int m = 32; m >= 1; m >>= 1) v += __shfl_xor(v, m, 64);
    return v;
}
__device__ __forceinline__ float sigm(float x) { return 1.f / (1.f + __expf(-x)); }

// decode 8 fp8(e4m3) + weighted accumulate
__device__ __forceinline__ void accum8_fp8(float* a, uint2 q, float w) {
    f32x2 c01 = __builtin_amdgcn_cvt_pk_f32_fp8((int)q.x, false);
    f32x2 c23 = __builtin_amdgcn_cvt_pk_f32_fp8((int)q.x, true);
    f32x2 c45 = __builtin_amdgcn_cvt_pk_f32_fp8((int)q.y, false);
    f32x2 c67 = __builtin_amdgcn_cvt_pk_f32_fp8((int)q.y, true);
    a[0] += w * c01[0]; a[1] += w * c01[1];
    a[2] += w * c23[0]; a[3] += w * c23[1];
    a[4] += w * c45[0]; a[5] += w * c45[1];
    a[6] += w * c67[0]; a[7] += w * c67[1];
}

// dual store: bf16 row (node-local consumers) + fp8 row (gather consumers)
__device__ __forceinline__ void store_dual(u32* dstb, u32* dst8, int node, int j, int sub, float o) {
    float po = __shfl_xor(o, 1, 64);
    if (!(sub & 1)) dstb[node * 64 + j * 8 + (sub >> 1)] = packbf(o, po);
    int pk = __builtin_amdgcn_cvt_pk_fp8_f32(o, po, 0, false);
    int pk2 = __shfl_xor(pk, 2, 64);
    if (!(sub & 3)) dst8[node * 32 + j * 4 + (sub >> 2)] = (u32)(pk & 0xffff) | ((u32)pk2 << 16);
}

// ---------- setup kernels ----------
__global__ void k_init(int* deg, float* oacc, u32* bars) {
    int i = blockIdx.x * blockDim.x + threadIdx.x;
    if (i < NN) deg[i] = 0;
    if (i < DH) oacc[i] = 0.f;
    if (i < 512) bars[i] = 0u;
}

__global__ void k_scalars(const float* meth, const float* hist, const float* logd,
                          const float* resw, float* sc) {
    float msum = 0.f;
    for (int j = 0; j < DH; j++) msum += sigm(meth[j]);
    float msil = msum * (1.f / DH);
    float h0 = sigm(hist[0]), h1 = sigm(hist[1]), h2 = sigm(hist[2]), h3 = sigm(hist[3]);
    float act = 0.5f * (h0 + h2), rep = 0.5f * (h1 + h3);
    float access = fminf(fmaxf(act - rep + 0.5f, 0.f), 1.f);
    sc[0] = access * (1.f - msil);
    float depth = fminf(fmaxf(__expf(logd[0]), 0.1f), 3.f);
    sc[1] = depth / (float)(TSTEPS - 1);
    sc[2] = resw[0];
}

__global__ void k_deg(const int* col, int* deg) {
    int e = blockIdx.x * blockDim.x + threadIdx.x;
    if (e < EE) atomicAdd(&deg[col[e]], 1);
}

__global__ __launch_bounds__(1024) void k_scan(const int* deg, int* offs, int* cursor, float* dis) {
    __shared__ int part[1024];
    const int CH = (NN + 1023) / 1024;
    int t = threadIdx.x;
    int base = t * CH;
    int s = 0;
    for (int k = 0; k < CH; k++) { int i = base + k; if (i < NN) s += deg[i]; }
    part[t] = s;
    __syncthreads();
    for (int off = 1; off < 1024; off <<= 1) {
        int v = part[t];
        int add = (t >= off) ? part[t - off] : 0;
        __syncthreads();
        part[t] = v + add;
        __syncthreads();
    }
    int run = part[t] - s;
    for (int k = 0; k < CH; k++) {
        int i = base + k;
        if (i < NN) {
            offs[i] = run; cursor[i] = run;
            int d = deg[i];
            run += d;
            dis[i] = (d > 0) ? rsqrtf((float)d) : 0.f;
        }
    }
    if (t == 1023) offs[NN] = run;
}

// edge record: (bf16 norm << 16) | src  (src < 20000 fits 16 bits)
__global__ void k_scatter(const int* row, const int* col, int* cursor, const float* dis,
                          u32* epk) {
    int e = blockIdx.x * blockDim.x + threadIdx.x;
    if (e < EE) {
        int c = col[e], r = row[e];
        int pos = atomicAdd(&cursor[c], 1);
        epk[pos] = (f2bf(dis[r] * dis[c]) << 16) | (u32)r;
    }
}

// ---------- fragment-order weight packing (known-good) ----------
__global__ void k_pack(const float* gcnw, const float* gatew, const float* Wo,
                       u32* wfrag, u32* gfrag, u32* wopk) {
    int tid = blockIdx.x * blockDim.x + threadIdx.x;
    if (tid < 6144) {                       // 3 layers * 4q * 8j * 64 lanes
        int lane = tid & 63, rem = tid >> 6;
        int j = rem & 7; rem >>= 3;
        int q = rem & 3; int l = rem >> 2;
        const float* W = gcnw + l * DH * DH;
        int r0 = 32 * q + 8 * (lane >> 4);
        int c  = 16 * j + (lane & 15);
        u32* o = wfrag + tid * 4;
#pragma unroll
        for (int p = 0; p < 4; p++)
            o[p] = packbf(W[(r0 + 2 * p) * DH + c], W[(r0 + 2 * p + 1) * DH + c]);
    } else if (tid < 6144 + 4096) {         // 8q * 8j * 64 lanes (gate 256x128)
        int t = tid - 6144;
        int lane = t & 63, rem = t >> 6;
        int j = rem & 7, q = rem >> 3;
        int r0 = 32 * q + 8 * (lane >> 4);
        int c  = 16 * j + (lane & 15);
        u32* o = gfrag + t * 4;
#pragma unroll
        for (int p = 0; p < 4; p++)
            o[p] = packbf(gatew[(r0 + 2 * p) * DH + c], gatew[(r0 + 2 * p + 1) * DH + c]);
    } else if (tid < 6144 + 4096 + 8192) {  // 64*128 u32 (Wo pair-packed)
        int t = tid - 10240;
        int k2 = t / DH, j = t % DH;
        wopk[t] = packbf(Wo[(2 * k2) * DH + j], Wo[(2 * k2 + 1) * DH + j]);
    }
}

// ---------- input projection: writes bf16 y, fp8 y8, fp32 hh ----------
__global__ __launch_bounds__(1024) void k_inproj(const float* x, const float* Wi, const float* bi,
                                                 const float* g, const float* b, const float* sc,
                                                 u32* y, u32* y8, float* hh) {
    __shared__ float Wl[DIN * DH];
    for (int i = threadIdx.x; i < DIN * DH; i += 1024) Wl[i] = Wi[i];
    __syncthreads();
    int wv = threadIdx.x >> 6, t = threadIdx.x & 63;
    int n = blockIdx.x * 16 + wv;
    if (n >= NN) return;
    float xv = x[n * DIN + t];
    float2 bb = *(const float2*)&bi[2 * t];
    float y0 = bb.x, y1 = bb.y;
#pragma unroll
    for (int k = 0; k < DIN; k++) {
        float a = __shfl(xv, k, 64);
        float2 w = *(const float2*)&Wl[k * DH + 2 * t];
        y0 += a * w.x; y1 += a * w.y;
    }
    float mu = wredsum(y0 + y1) * (1.f / DH);
    float d0 = y0 - mu, d1 = y1 - mu;
    float var = wredsum(d0 * d0 + d1 * d1) * (1.f / DH);
    float r = rsqrtf(var + LNEPS);
    float2 gg = *(const float2*)&g[2 * t], lb = *(const float2*)&b[2 * t];
    float scale = sc[0];
    float v0 = fmaxf(d0 * r * gg.x + lb.x, 0.f) * scale;
    float v1 = fmaxf(d1 * r * gg.y + lb.y, 0.f) * scale;
    y[n * 64 + t] = packbf(v0, v1);
    *(float2*)&hh[n * DH + 2 * t] = make_float2(v0, v1);
    int pk = __builtin_amdgcn_cvt_pk_fp8_f32(v0, v1, 0, false);
    int pk2 = __shfl_xor(pk, 1, 64);
    if (!(t & 1)) y8[n * 32 + (t >> 1)] = (u32)(pk & 0xffff) | ((u32)pk2 << 16);
}

// ---------- gather ONE row per quarter-wave from fp8 rows, 8 loads in flight ----------
__device__ __forceinline__ void gather_row(const u32* __restrict__ src8, u32* tile,
                                           int row, int sub, int qb, int e0, int e1,
                                           const u32* __restrict__ epk) {
    float a[8] = {0.f, 0.f, 0.f, 0.f, 0.f, 0.f, 0.f, 0.f};
    for (int eb = e0; eb < e1; eb += 16) {
        int cc = min(16, e1 - eb);
        u32 p = 0;
        if (sub < cc) p = epk[eb + sub];
        {
            u32 pe[8]; uint2 q[8];
#pragma unroll
            for (int u = 0; u < 8; u++) pe[u] = (u32)__shfl((int)p, qb + u, 64);
#pragma unroll
            for (int u = 0; u < 8; u++)
                q[u] = *(const uint2*)(src8 + (pe[u] & 0xffffu) * 32 + sub * 2);
#pragma unroll
            for (int u = 0; u < 8; u++)
                accum8_fp8(a, q[u], __uint_as_float(pe[u] & 0xffff0000u));
        }
        if (cc > 8) {
            u32 pe[8]; uint2 q[8];
#pragma unroll
            for (int u = 0; u < 8; u++) pe[u] = (u32)__shfl((int)p, qb + 8 + u, 64);
#pragma unroll
            for (int u = 0; u < 8; u++)
                q[u] = *(const uint2*)(src8 + (pe[u] & 0xffffu) * 32 + sub * 2);
#pragma unroll
            for (int u = 0; u < 8; u++)
                accum8_fp8(a, q[u], __uint_as_float(pe[u] & 0xffff0000u));
        }
    }
    uint4 v;
    v.x = packbf(a[0], a[1]); v.y = packbf(a[2], a[3]);
    v.z = packbf(a[4], a[5]); v.w = packbf(a[6], a[7]);
    *(uint4*)(tile + row * 68 + sub * 4) = v;
}

// ---------- phase bodies (identical math to round-7 verified kernels) ----------
__device__ __forceinline__ void body_aggmm(const u32* __restrict__ src8,
                                           u32* __restrict__ dstb, u32* __restrict__ dst8,
                                           const u32* __restrict__ wfrag,
                                           const float* __restrict__ bias,
                                           const float* __restrict__ lng,
                                           const float* __restrict__ lnb,
                                           const u32* __restrict__ epk,
                                           u32* tile, float (*lred1)[16], float (*lred2)[16],
                                           int wv, int lane, int base, int e0, int e1) {
    int t4 = lane >> 4, sub = lane & 15;
    int row = wv * 4 + t4;
    gather_row(src8, tile, row, sub, t4 * 16, e0, e1, epk);
    __syncthreads();

    f32x4 acc[2];
#pragma unroll
    for (int jl = 0; jl < 2; jl++) acc[jl] = (f32x4){0.f, 0.f, 0.f, 0.f};
#pragma unroll
    for (int q = 0; q < 4; q++) {
        bf16x8 A = *(const bf16x8*)(tile + sub * 68 + q * 16 + t4 * 4);
#pragma unroll
        for (int jl = 0; jl < 2; jl++) {
            int j = 2 * wv + jl;
            bf16x8 B = *(const bf16x8*)(wfrag + ((q * 8 + j) * 64 + lane) * 4);
            acc[jl] = __builtin_amdgcn_mfma_f32_16x16x32_bf16(A, B, acc[jl], 0, 0, 0);
        }
    }
    float s1[4] = {0.f, 0.f, 0.f, 0.f}, s2[4] = {0.f, 0.f, 0.f, 0.f};
#pragma unroll
    for (int jl = 0; jl < 2; jl++) {
        float bb = bias[16 * (2 * wv + jl) + sub];
#pragma unroll
        for (int r = 0; r < 4; r++) {
            float v = acc[jl][r] + bb;
            acc[jl][r] = v;
            s1[r] += v; s2[r] += v * v;
        }
    }
#pragma unroll
    for (int r = 0; r < 4; r++) {
#pragma unroll
        for (int m = 1; m <= 8; m <<= 1) {
            s1[r] += __shfl_xor(s1[r], m, 64);
            s2[r] += __shfl_xor(s2[r], m, 64);
        }
        if (sub == 0) { lred1[wv][4 * t4 + r] = s1[r]; lred2[wv][4 * t4 + r] = s2[r]; }
    }
    __syncthreads();
    float mu[4], rs[4];
#pragma unroll
    for (int r = 0; r < 4; r++) {
        int n16 = 4 * t4 + r;
        float t1 = lred1[0][n16] + lred1[1][n16] + lred1[2][n16] + lred1[3][n16];
        float t2 = lred2[0][n16] + lred2[1][n16] + lred2[2][n16] + lred2[3][n16];
        mu[r] = t1 * (1.f / DH);
        float var = t2 * (1.f / DH) - mu[r] * mu[r];
        rs[r] = rsqrtf(var + LNEPS);
    }
#pragma unroll
    for (int jl = 0; jl < 2; jl++) {
        int j = 2 * wv + jl;
        float gg = lng[16 * j + sub], be = lnb[16 * j + sub];
#pragma unroll
        for (int r = 0; r < 4; r++) {
            float o = (acc[jl][r] - mu[r]) * rs[r] * gg + be;
            store_dual(dstb, dst8, base + 4 * t4 + r, j, sub, o);
        }
    }
}

template <bool LAST>
__device__ __forceinline__ void body_fused(const u32* __restrict__ srcb,
                                           const u32* __restrict__ src8,
                                           u32* __restrict__ dstb, u32* __restrict__ dst8,
                                           const u32* __restrict__ wfragL,
                                           const float* __restrict__ bias,
                                           const float* __restrict__ lng,
                                           const float* __restrict__ lnb,
                                           const u32* __restrict__ gfrag,
                                           const float* __restrict__ gateb,
                                           float* __restrict__ hh,
                                           unsigned short* __restrict__ acc_g,
                                           const float* __restrict__ sc, int rkj,
                                           const u32* __restrict__ epk,
                                           u32* tile, float (*lred1)[16], float (*lred2)[16],
                                           int wv, int lane, int base, int e0, int e1) {
    int t4 = lane >> 4, sub = lane & 15;
    int row = wv * 4 + t4;

    // prefetch own-node A-frags (gate first half) — overlaps gather latency
    bf16x8 Ahc[4];
#pragma unroll
    for (int q = 0; q < 4; q++)
        Ahc[q] = *(const bf16x8*)(srcb + (base + sub) * 64 + q * 16 + t4 * 4);

    // LAST: prefetch cold epilogue operands (hh, residual row, RK4 acc)
    float hv_p[2][4]; u32 py_p[2][4]; float av_p[2][4];
    if (LAST) {
#pragma unroll
        for (int jl = 0; jl < 2; jl++) {
            int j = 2 * wv + jl;
#pragma unroll
            for (int r = 0; r < 4; r++) {
                int node = base + 4 * t4 + r;
                int fi = node * DH + 16 * j + sub;
                hv_p[jl][r] = hh[fi];
                py_p[jl][r] = dstb[node * 64 + j * 8 + (sub >> 1)];
                av_p[jl][r] = (rkj != 0) ? __uint_as_float((u32)acc_g[fi] << 16) : 0.f;
            }
        }
    }

    gather_row(src8, tile, row, sub, t4 * 16, e0, e1, epk);
    __syncthreads();

    // GEMM1: this wave's 2 output j's only
    f32x4 acc[2];
#pragma unroll
    for (int jl = 0; jl < 2; jl++) acc[jl] = (f32x4){0.f, 0.f, 0.f, 0.f};
#pragma unroll
    for (int q = 0; q < 4; q++) {
        bf16x8 A = *(const bf16x8*)(tile + sub * 68 + q * 16 + t4 * 4);
#pragma unroll
        for (int jl = 0; jl < 2; jl++) {
            int j = 2 * wv + jl;
            bf16x8 B = *(const bf16x8*)(wfragL + ((q * 8 + j) * 64 + lane) * 4);
            acc[jl] = __builtin_amdgcn_mfma_f32_16x16x32_bf16(A, B, acc[jl], 0, 0, 0);
        }
    }

    // bias + partial LN sums -> LDS cross-wave reduce
    float s1[4] = {0.f, 0.f, 0.f, 0.f}, s2[4] = {0.f, 0.f, 0.f, 0.f};
#pragma unroll
    for (int jl = 0; jl < 2; jl++) {
        float bb = bias[16 * (2 * wv + jl) + sub];
#pragma unroll
        for (int r = 0; r < 4; r++) {
            float v = acc[jl][r] + bb;
            acc[jl][r] = v;
            s1[r] += v; s2[r] += v * v;
        }
    }
#pragma unroll
    for (int r = 0; r < 4; r++) {
#pragma unroll
        for (int m = 1; m <= 8; m <<= 1) {
            s1[r] += __shfl_xor(s1[r], m, 64);
            s2[r] += __shfl_xor(s2[r], m, 64);
        }
        if (sub == 0) { lred1[wv][4 * t4 + r] = s1[r]; lred2[wv][4 * t4 + r] = s2[r]; }
    }
    __syncthreads();   // also guarantees all GEMM1 tile reads done
    float mu[4], rs[4];
#pragma unroll
    for (int r = 0; r < 4; r++) {
        int n16 = 4 * t4 + r;
        float t1 = lred1[0][n16] + lred1[1][n16] + lred1[2][n16] + lred1[3][n16];
        float t2 = lred2[0][n16] + lred2[1][n16] + lred2[2][n16] + lred2[3][n16];
        mu[r] = t1 * (1.f / DH);
        float var = t2 * (1.f / DH) - mu[r] * mu[r];
        rs[r] = rsqrtf(var + LNEPS);
    }
#pragma unroll
    for (int jl = 0; jl < 2; jl++) {
        int j = 2 * wv + jl;
        float gg = lng[16 * j + sub], be = lnb[16 * j + sub];
#pragma unroll
        for (int r = 0; r < 4; r++)
            acc[jl][r] = (acc[jl][r] - mu[r]) * rs[r] * gg + be;
    }

    // hn -> tile (A-layout): each wave writes its own 32-col slice (disjoint)
#pragma unroll
    for (int jl = 0; jl < 2; jl++) {
        int j = 2 * wv + jl;
#pragma unroll
        for (int r = 0; r < 4; r++) {
            float o = acc[jl][r];
            float po = __shfl_xor(o, 1, 64);
            if (!(sub & 1)) tile[(4 * t4 + r) * 68 + j * 8 + (sub >> 1)] = packbf(o, po);
        }
    }
    __syncthreads();

    // GEMM2: gate logits (K=256), this wave's 2 j's; hn A-frags read from LDS
    f32x4 ag[2];
#pragma unroll
    for (int jl = 0; jl < 2; jl++) ag[jl] = (f32x4){0.f, 0.f, 0.f, 0.f};
#pragma unroll
    for (int q = 0; q < 8; q++) {
        bf16x8 A = (q < 4) ? Ahc[q]
                           : *(const bf16x8*)(tile + sub * 68 + (q - 4) * 16 + t4 * 4);
#pragma unroll
        for (int jl = 0; jl < 2; jl++) {
            int j = 2 * wv + jl;
            bf16x8 B = *(const bf16x8*)(gfrag + ((q * 8 + j) * 64 + lane) * 4);
            ag[jl] = __builtin_amdgcn_mfma_f32_16x16x32_bf16(A, B, ag[jl], 0, 0, 0);
        }
    }

    // epilogue for own j's
    float dt = 0.f, rw = 0.f;
    if (LAST) { dt = sc[1]; rw = sc[2]; }
#pragma unroll
    for (int jl = 0; jl < 2; jl++) {
        int j = 2 * wv + jl;
        float gbj = gateb[16 * j + sub];
#pragma unroll
        for (int r = 0; r < 4; r++) {
            int node = base + 4 * t4 + r;
            int ui = node * 64 + j * 8 + (sub >> 1);
            float g = sigm(ag[jl][r] + gbj);
            u32 pc = srcb[ui];   // L1-warm (same rows as Ahc)
            float hcv = (sub & 1) ? bfhi(pc) : bflo(pc);
            float o = g * acc[jl][r] + (1.f - g) * hcv;
            if (!LAST) {
                store_dual(dstb, dst8, node, j, sub, o);
            } else {
                float z = fminf(fmaxf(o, -15.f), 15.f);
                float e = __expf(2.f * z);
                float th = (e - 1.f) / (e + 1.f);
                float yv = (sub & 1) ? bfhi(py_p[jl][r]) : bflo(py_p[jl][r]);
                float kk = th + rw * yv;
                float wj = dt * (1.f / 6.f) * ((rkj == 1 || rkj == 2) ? 2.f : 1.f);
                int fi = node * DH + 16 * j + sub;
                float av = wj * kk + av_p[jl][r];
                acc_g[fi] = (unsigned short)f2bf(av);
                float hv = hv_p[jl][r];
                if (rkj < 3) {
                    float c = (rkj == 2) ? dt : 0.5f * dt;
                    store_dual(dstb, dst8, node, j, sub, hv + c * kk);
                } else {
                    float f = hv + av;
                    hh[fi] = f;
                    store_dual(dstb, dst8, node, j, sub, f);
                }
            }
        }
    }
}

// ---------- hierarchical grid barrier (r4 fix: release=writeback only; ----------
// ---------- invalidate clustered AFTER global arrival; 8 padded counters) ------
__device__ __forceinline__ void pbar(u32* bars, u32 phase) {
    __syncthreads();
    if (threadIdx.x == 0) {
        int grp = blockIdx.x & 7;
        u32 per = (grp < (NCHUNK & 7)) ? (u32)(NCHUNK / 8 + 1) : (u32)(NCHUNK / 8);
        // arrival: RELEASE (L2 writeback, NO invalidate) — own 128B line per group
        u32 old = __hip_atomic_fetch_add(&bars[grp * 32], 1u, __ATOMIC_RELEASE,
                                         __HIP_MEMORY_SCOPE_AGENT);
        if (old == phase * per - 1u) {     // last arriver of this group
            u32 g = __hip_atomic_fetch_add(&bars[256], 1u, __ATOMIC_RELEASE,
                                           __HIP_MEMORY_SCOPE_AGENT);
            if (g == phase * 8u - 1u)      // last group
                __hip_atomic_store(&bars[288], phase, __ATOMIC_RELEASE,
                                   __HIP_MEMORY_SCOPE_AGENT);
        }
        // poll release flag (read-only line, backoff ~2k cycles)
        while (__hip_atomic_load(&bars[288], __ATOMIC_RELAXED, __HIP_MEMORY_SCOPE_AGENT) < phase)
            __builtin_amdgcn_s_sleep(32);
        // acquire: invalidate L1/L2 — clustered, nobody is mid-phase now
        (void)__hip_atomic_load(&bars[288], __ATOMIC_ACQUIRE, __HIP_MEMORY_SCOPE_AGENT);
    }
    __syncthreads();
}

// ---------- persistent ODE kernel: 19 steps x 4 RK stages x 3 layers ----------
__global__ __launch_bounds__(256, 5) void k_ode(u32* y, u32* y8, u32* hc, u32* hc8,
                                                u32* hc2, u32* hc28,
                                                const u32* __restrict__ wfrag,
                                                const u32* __restrict__ gfrag,
                                                const float* __restrict__ gcnb,
                                                const float* __restrict__ lng,
                                                const float* __restrict__ lnb,
                                                const float* __restrict__ gateb,
                                                float* __restrict__ hh,
                                                unsigned short* __restrict__ accg,
                                                const float* __restrict__ sc,
                                                const int* __restrict__ offs,
                                                const u32* __restrict__ epk,
                                                u32* bars) {
    __shared__ u32 tile[16 * 68];
    __shared__ float lred1[4][16], lred2[4][16];
    int wv = threadIdx.x >> 6, lane = threadIdx.x & 63;
    int base = blockIdx.x * 16;
    int t4 = lane >> 4;
    int row = wv * 4 + t4;
    // row CSR bounds are invariant across all 228 phases — cache in registers
    int e0 = offs[base + row], e1 = offs[base + row + 1];

    const int LSZ = 32 * 64 * 4;
    u32 phase = 0;
    for (int s = 0; s < TSTEPS - 1; s++) {
        for (int j = 0; j < 4; j++) {
            body_aggmm(y8, hc, hc8, wfrag, gcnb, lng, lnb, epk,
                       tile, lred1, lred2, wv, lane, base, e0, e1);
            pbar(bars, ++phase);
            body_fused<false>(hc, hc8, hc2, hc28, wfrag + LSZ, gcnb + DH, lng + DH, lnb + DH,
                              gfrag, gateb, nullptr, nullptr, sc, j, epk,
                              tile, lred1, lred2, wv, lane, base, e0, e1);
            pbar(bars, ++phase);
            body_fused<true>(hc2, hc28, y, y8, wfrag + 2 * LSZ, gcnb + 2 * DH, lng + 2 * DH,
                             lnb + 2 * DH, gfrag, gateb, hh, accg, sc, j, epk,
                             tile, lred1, lred2, wv, lane, base, e0, e1);
            pbar(bars, ++phase);
        }
    }
}

// ---------- output projection + LN + global mean (known-good) ----------
__global__ __launch_bounds__(1024) void k_outproj(const float* __restrict__ hh, const u32* wopk,
                                                  const float* bo, const float* g, const float* b,
                                                  float* oacc) {
    __shared__ u32 Wl[64 * DH];
    __shared__ float red[DH];
    for (int i = threadIdx.x; i < 64 * DH; i += 1024) Wl[i] = wopk[i];
    if (threadIdx.x < DH) red[threadIdx.x] = 0.f;
    __syncthreads();
    int wv = threadIdx.x >> 6, t = threadIdx.x & 63;
    int n = blockIdx.x * 16 + wv;
    if (n < NN) {
        float2 hv = *(const float2*)&hh[n * DH + 2 * t];
        float h0 = hv.x, h1 = hv.y;
        float2 bb = *(const float2*)&bo[2 * t];
        float y0 = bb.x, y1 = bb.y;
#pragma unroll
        for (int k2 = 0; k2 < 64; k2++) {
            float a0 = __shfl(h0, k2, 64), a1 = __shfl(h1, k2, 64);
            uint2 wq = *(const uint2*)&Wl[k2 * DH + 2 * t];
            y0 += a0 * bflo(wq.x) + a1 * bfhi(wq.x);
            y1 += a0 * bflo(wq.y) + a1 * bfhi(wq.y);
        }
        float mu = wredsum(y0 + y1) * (1.f / DH);
        float d0 = y0 - mu, d1 = y1 - mu;
        float var = wredsum(d0 * d0 + d1 * d1) * (1.f / DH);
        float r = rsqrtf(var + LNEPS);
        float2 gg = *(const float2*)&g[2 * t], lb = *(const float2*)&b[2 * t];
        atomicAdd(&red[2 * t], d0 * r * gg.x + lb.x);
        atomicAdd(&red[2 * t + 1], d1 * r * gg.y + lb.y);
    }
    __syncthreads();
    if (threadIdx.x < DH) atomicAdd(&oacc[threadIdx.x], red[threadIdx.x]);
}

__global__ void k_final(const float* oacc, float* out) {
    int t = threadIdx.x;
    if (t < DH) out[t] = oacc[t] * (1.f / (float)NN);
}

// ---------- host ----------
extern "C" void kernel_launch(void* const* d_in, const int* in_sizes, int n_in,
                              void* d_out, int out_size, void* d_ws, size_t ws_size,
                              hipStream_t stream) {
    const float* x     = (const float*)d_in[0];
    const int*   ei    = (const int*)d_in[1];
    const float* Wi    = (const float*)d_in[2];
    const float* bi    = (const float*)d_in[3];
    const float* ling  = (const float*)d_in[4];
    const float* linb  = (const float*)d_in[5];
    const float* meth  = (const float*)d_in[6];
    const float* hist  = (const float*)d_in[7];
    const float* gcnw  = (const float*)d_in[8];
    const float* gcnb  = (const float*)d_in[9];
    const float* lng   = (const float*)d_in[10];
    const float* lnb   = (const float*)d_in[11];
    const float* gatew = (const float*)d_in[12];
    const float* gateb = (const float*)d_in[13];
    const float* resw  = (const float*)d_in[14];
    const float* logd  = (const float*)d_in[15];
    const float* Wo    = (const float*)d_in[16];
    const float* bo    = (const float*)d_in[17];
    const float* loutg = (const float*)d_in[18];
    const float* loutb = (const float*)d_in[19];

    char* wsb = (char*)d_ws;
    size_t off = 0;
    auto alloc = [&](size_t bytes) -> void* {
        void* p = wsb + off;
        off += (bytes + 255) & ~(size_t)255;
        return p;
    };
    float* sc     = (float*)alloc(32);
    u32*   bars   = (u32*)alloc(512 * 4);   // padded barrier counters
    int*   deg    = (int*)alloc(NN * 4);
    int*   offs   = (int*)alloc((NN + 1) * 4);
    int*   cursor = (int*)alloc(NN * 4);
    float* dis    = (float*)alloc(NN * 4);
    u32*   epk    = (u32*)alloc(EE * 4);
    u32*   wfrag  = (u32*)alloc(3 * 32 * 64 * 4 * 4);
    u32*   gfrag  = (u32*)alloc(64 * 64 * 4 * 4);
    u32*   wopk   = (u32*)alloc(64 * DH * 4);
    u32*   y      = (u32*)alloc((size_t)NN * 64 * 4);   // bf16 rows
    u32*   hc     = (u32*)alloc((size_t)NN * 64 * 4);
    u32*   hc2    = (u32*)alloc((size_t)NN * 64 * 4);
    u32*   y8     = (u32*)alloc((size_t)NN * 32 * 4);   // fp8 rows (gather)
    u32*   hc8    = (u32*)alloc((size_t)NN * 32 * 4);
    u32*   hc28   = (u32*)alloc((size_t)NN * 32 * 4);
    float* hh     = (float*)alloc((size_t)NN * DH * 4);
    unsigned short* accg = (unsigned short*)alloc((size_t)NN * DH * 2);
    float* oacc   = (float*)alloc(DH * 4);

    const int* row = ei;
    const int* col = ei + EE;

    k_init<<<(NN + 255) / 256, 256, 0, stream>>>(deg, oacc, bars);
    k_scalars<<<1, 1, 0, stream>>>(meth, hist, logd, resw, sc);
    k_deg<<<(EE + 255) / 256, 256, 0, stream>>>(col, deg);
    k_scan<<<1, 1024, 0, stream>>>(deg, offs, cursor, dis);
    k_scatter<<<(EE + 255) / 256, 256, 0, stream>>>(row, col, cursor, dis, epk);
    k_pack<<<(6144 + 4096 + 8192 + 255) / 256, 256, 0, stream>>>(gcnw, gatew, Wo, wfrag, gfrag, wopk);

    const int GB1 = (NN + 15) / 16;
    k_inproj<<<GB1, 1024, 0, stream>>>(x, Wi, bi, ling, linb, sc, y, y8, hh);

    // persistent: 1250 blocks x 256 thr; launch_bounds(256,5) -> 5 blocks/CU
    // -> capacity 1280 >= 1250, all resident (required for the grid barrier)
    k_ode<<<NCHUNK, 256, 0, stream>>>(y, y8, hc, hc8, hc2, hc28, wfrag, gfrag,
                                      gcnb, lng, lnb, gateb, hh, accg, sc, offs, epk, bars);

    k_outproj<<<GB1, 1024, 0, stream>>>(hh, wopk, bo, loutg, loutb, oacc);
    k_final<<<1, 128, 0, stream>>>(oacc, (float*)d_out);
}

// Round 9
// 28132.190 us; speedup vs baseline: 1.0778x; 1.0778x over previous
//
#include <hip/hip_runtime.h>

typedef unsigned int u32;
typedef unsigned long long u64;
using bf16x8 = __attribute__((ext_vector_type(8))) short;
using f32x4  = __attribute__((ext_vector_type(4))) float;
using f32x2  = __attribute__((ext_vector_type(2))) float;

#define NN 20000
#define EE 320000
#define DH 128
#define DIN 64
#define TSTEPS 20
#define LNEPS 1e-5f
#define NCHUNK 1250   // 20000 / 16-node chunks; 1 persistent block per chunk

// ---------- helpers ----------
__device__ __forceinline__ u32 f2bf(float f) {
    u32 x = __float_as_uint(f);
    return (x + 0x7fffu + ((x >> 16) & 1u)) >> 16;   // RNE to bf16 bits
}
__device__ __forceinline__ float bflo(u32 p) { return __uint_as_float(p << 16); }
__device__ __forceinline__ float bfhi(u32 p) { return __uint_as_float(p & 0xffff0000u); }
__device__ __forceinline__ u32 packbf(float a, float b) { return f2bf(a) | (f2bf(b) << 16); }
__device__ __forceinline__ float wredsum(float v) {
#pragma unroll
    for (int m = 32; m >= 1; m >>= 1) v += __shfl_xor(v, m, 64);
    return v;
}
__device__ __forceinline__ float sigm(float x) { return 1.f / (1.f + __expf(-x)); }

// LLC-coherent (sc1) access for the cross-block fp8 state arrays:
// never cached in per-XCD L2 -> no barrier invalidate needed.
__device__ __forceinline__ uint2 llc_load8(const u32* p) {
    u64 v = __hip_atomic_load((u64*)p, __ATOMIC_RELAXED, __HIP_MEMORY_SCOPE_AGENT);
    uint2 q; q.x = (u32)v; q.y = (u32)(v >> 32);
    return q;
}
__device__ __forceinline__ void llc_store4(u32* p, u32 v) {
    __hip_atomic_store(p, v, __ATOMIC_RELAXED, __HIP_MEMORY_SCOPE_AGENT);
}

// decode 8 fp8(e4m3) + weighted accumulate
__device__ __forceinline__ void accum8_fp8(float* a, uint2 q, float w) {
    f32x2 c01 = __builtin_amdgcn_cvt_pk_f32_fp8((int)q.x, false);
    f32x2 c23 = __builtin_amdgcn_cvt_pk_f32_fp8((int)q.x, true);
    f32x2 c45 = __builtin_amdgcn_cvt_pk_f32_fp8((int)q.y, false);
    f32x2 c67 = __builtin_amdgcn_cvt_pk_f32_fp8((int)q.y, true);
    a[0] += w * c01[0]; a[1] += w * c01[1];
    a[2] += w * c23[0]; a[3] += w * c23[1];
    a[4] += w * c45[0]; a[5] += w * c45[1];
    a[6] += w * c67[0]; a[7] += w * c67[1];
}

// dual store: bf16 row (block-local consumers, normal cached store) +
// fp8 row (cross-block gather consumers, sc1 write-through)
__device__ __forceinline__ void store_dual(u32* dstb, u32* dst8, int node, int j, int sub, float o) {
    float po = __shfl_xor(o, 1, 64);
    if (!(sub & 1)) dstb[node * 64 + j * 8 + (sub >> 1)] = packbf(o, po);
    int pk = __builtin_amdgcn_cvt_pk_fp8_f32(o, po, 0, false);
    int pk2 = __shfl_xor(pk, 2, 64);
    if (!(sub & 3)) llc_store4(&dst8[node * 32 + j * 4 + (sub >> 2)],
                               (u32)(pk & 0xffff) | ((u32)pk2 << 16));
}

// ---------- setup kernels ----------
__global__ void k_init(int* deg, float* oacc, u32* bars) {
    int i = blockIdx.x * blockDim.x + threadIdx.x;
    if (i < NN) deg[i] = 0;
    if (i < DH) oacc[i] = 0.f;
    if (i < 512) bars[i] = 0u;
}

__global__ void k_scalars(const float* meth, const float* hist, const float* logd,
                          const float* resw, float* sc) {
    float msum = 0.f;
    for (int j = 0; j < DH; j++) msum += sigm(meth[j]);
    float msil = msum * (1.f / DH);
    float h0 = sigm(hist[0]), h1 = sigm(hist[1]), h2 = sigm(hist[2]), h3 = sigm(hist[3]);
    float act = 0.5f * (h0 + h2), rep = 0.5f * (h1 + h3);
    float access = fminf(fmaxf(act - rep + 0.5f, 0.f), 1.f);
    sc[0] = access * (1.f - msil);
    float depth = fminf(fmaxf(__expf(logd[0]), 0.1f), 3.f);
    sc[1] = depth / (float)(TSTEPS - 1);
    sc[2] = resw[0];
}

__global__ void k_deg(const int* col, int* deg) {
    int e = blockIdx.x * blockDim.x + threadIdx.x;
    if (e < EE) atomicAdd(&deg[col[e]], 1);
}

__global__ __launch_bounds__(1024) void k_scan(const int* deg, int* offs, int* cursor, float* dis) {
    __shared__ int part[1024];
    const int CH = (NN + 1023) / 1024;
    int t = threadIdx.x;
    int base = t * CH;
    int s = 0;
    for (int k = 0; k < CH; k++) { int i = base + k; if (i < NN) s += deg[i]; }
    part[t] = s;
    __syncthreads();
    for (int off = 1; off < 1024; off <<= 1) {
        int v = part[t];
        int add = (t >= off) ? part[t - off] : 0;
        __syncthreads();
        part[t] = v + add;
        __syncthreads();
    }
    int run = part[t] - s;
    for (int k = 0; k < CH; k++) {
        int i = base + k;
        if (i < NN) {
            offs[i] = run; cursor[i] = run;
            int d = deg[i];
            run += d;
            dis[i] = (d > 0) ? rsqrtf((float)d) : 0.f;
        }
    }
    if (t == 1023) offs[NN] = run;
}

// edge record: (bf16 norm << 16) | src  (src < 20000 fits 16 bits)
__global__ void k_scatter(const int* row, const int* col, int* cursor, const float* dis,
                          u32* epk) {
    int e = blockIdx.x * blockDim.x + threadIdx.x;
    if (e < EE) {
        int c = col[e], r = row[e];
        int pos = atomicAdd(&cursor[c], 1);
        epk[pos] = (f2bf(dis[r] * dis[c]) << 16) | (u32)r;
    }
}

// ---------- fragment-order weight packing (known-good) ----------
__global__ void k_pack(const float* gcnw, const float* gatew, const float* Wo,
                       u32* wfrag, u32* gfrag, u32* wopk) {
    int tid = blockIdx.x * blockDim.x + threadIdx.x;
    if (tid < 6144) {                       // 3 layers * 4q * 8j * 64 lanes
        int lane = tid & 63, rem = tid >> 6;
        int j = rem & 7; rem >>= 3;
        int q = rem & 3; int l = rem >> 2;
        const float* W = gcnw + l * DH * DH;
        int r0 = 32 * q + 8 * (lane >> 4);
        int c  = 16 * j + (lane & 15);
        u32* o = wfrag + tid * 4;
#pragma unroll
        for (int p = 0; p < 4; p++)
            o[p] = packbf(W[(r0 + 2 * p) * DH + c], W[(r0 + 2 * p + 1) * DH + c]);
    } else if (tid < 6144 + 4096) {         // 8q * 8j * 64 lanes (gate 256x128)
        int t = tid - 6144;
        int lane = t & 63, rem = t >> 6;
        int j = rem & 7, q = rem >> 3;
        int r0 = 32 * q + 8 * (lane >> 4);
        int c  = 16 * j + (lane & 15);
        u32* o = gfrag + t * 4;
#pragma unroll
        for (int p = 0; p < 4; p++)
            o[p] = packbf(gatew[(r0 + 2 * p) * DH + c], gatew[(r0 + 2 * p + 1) * DH + c]);
    } else if (tid < 6144 + 4096 + 8192) {  // 64*128 u32 (Wo pair-packed)
        int t = tid - 10240;
        int k2 = t / DH, j = t % DH;
        wopk[t] = packbf(Wo[(2 * k2) * DH + j], Wo[(2 * k2 + 1) * DH + j]);
    }
}

// ---------- input projection: writes bf16 y, fp8 y8, fp32 hh ----------
// (normal stores: kernel boundary writes back L2 before k_ode starts)
__global__ __launch_bounds__(1024) void k_inproj(const float* x, const float* Wi, const float* bi,
                                                 const float* g, const float* b, const float* sc,
                                                 u32* y, u32* y8, float* hh) {
    __shared__ float Wl[DIN * DH];
    for (int i = threadIdx.x; i < DIN * DH; i += 1024) Wl[i] = Wi[i];
    __syncthreads();
    int wv = threadIdx.x >> 6, t = threadIdx.x & 63;
    int n = blockIdx.x * 16 + wv;
    if (n >= NN) return;
    float xv = x[n * DIN + t];
    float2 bb = *(const float2*)&bi[2 * t];
    float y0 = bb.x, y1 = bb.y;
#pragma unroll
    for (int k = 0; k < DIN; k++) {
        float a = __shfl(xv, k, 64);
        float2 w = *(const float2*)&Wl[k * DH + 2 * t];
        y0 += a * w.x; y1 += a * w.y;
    }
    float mu = wredsum(y0 + y1) * (1.f / DH);
    float d0 = y0 - mu, d1 = y1 - mu;
    float var = wredsum(d0 * d0 + d1 * d1) * (1.f / DH);
    float r = rsqrtf(var + LNEPS);
    float2 gg = *(const float2*)&g[2 * t], lb = *(const float2*)&b[2 * t];
    float scale = sc[0];
    float v0 = fmaxf(d0 * r * gg.x + lb.x, 0.f) * scale;
    float v1 = fmaxf(d1 * r * gg.y + lb.y, 0.f) * scale;
    y[n * 64 + t] = packbf(v0, v1);
    *(float2*)&hh[n * DH + 2 * t] = make_float2(v0, v1);
    int pk = __builtin_amdgcn_cvt_pk_fp8_f32(v0, v1, 0, false);
    int pk2 = __shfl_xor(pk, 1, 64);
    if (!(t & 1)) y8[n * 32 + (t >> 1)] = (u32)(pk & 0xffff) | ((u32)pk2 << 16);
}

// ---------- gather ONE row per quarter-wave from fp8 rows (sc1 loads) ----------
__device__ __forceinline__ void gather_row(const u32* __restrict__ src8, u32* tile,
                                           int row, int sub, int qb, int e0, int e1,
                                           const u32* __restrict__ epk) {
    float a[8] = {0.f, 0.f, 0.f, 0.f, 0.f, 0.f, 0.f, 0.f};
    for (int eb = e0; eb < e1; eb += 16) {
        int cc = min(16, e1 - eb);
        u32 p = 0;
        if (sub < cc) p = epk[eb + sub];
        {
            u32 pe[8]; uint2 q[8];
#pragma unroll
            for (int u = 0; u < 8; u++) pe[u] = (u32)__shfl((int)p, qb + u, 64);
#pragma unroll
            for (int u = 0; u < 8; u++)
                q[u] = llc_load8(src8 + (pe[u] & 0xffffu) * 32 + sub * 2);
#pragma unroll
            for (int u = 0; u < 8; u++)
                accum8_fp8(a, q[u], __uint_as_float(pe[u] & 0xffff0000u));
        }
        if (cc > 8) {
            u32 pe[8]; uint2 q[8];
#pragma unroll
            for (int u = 0; u < 8; u++) pe[u] = (u32)__shfl((int)p, qb + 8 + u, 64);
#pragma unroll
            for (int u = 0; u < 8; u++)
                q[u] = llc_load8(src8 + (pe[u] & 0xffffu) * 32 + sub * 2);
#pragma unroll
            for (int u = 0; u < 8; u++)
                accum8_fp8(a, q[u], __uint_as_float(pe[u] & 0xffff0000u));
        }
    }
    uint4 v;
    v.x = packbf(a[0], a[1]); v.y = packbf(a[2], a[3]);
    v.z = packbf(a[4], a[5]); v.w = packbf(a[6], a[7]);
    *(uint4*)(tile + row * 68 + sub * 4) = v;
}

// ---------- phase bodies (math identical to round-7/8 verified kernels) ----------
__device__ __forceinline__ void body_aggmm(const u32* __restrict__ src8,
                                           u32* __restrict__ dstb, u32* __restrict__ dst8,
                                           const u32* __restrict__ wfrag,
                                           const float* __restrict__ bias,
                                           const float* __restrict__ lng,
                                           const float* __restrict__ lnb,
                                           const u32* __restrict__ epk,
                                           u32* tile, float (*lred1)[16], float (*lred2)[16],
                                           int wv, int lane, int base, int e0, int e1) {
    int t4 = lane >> 4, sub = lane & 15;
    int row = wv * 4 + t4;
    gather_row(src8, tile, row, sub, t4 * 16, e0, e1, epk);
    __syncthreads();

    f32x4 acc[2];
#pragma unroll
    for (int jl = 0; jl < 2; jl++) acc[jl] = (f32x4){0.f, 0.f, 0.f, 0.f};
#pragma unroll
    for (int q = 0; q < 4; q++) {
        bf16x8 A = *(const bf16x8*)(tile + sub * 68 + q * 16 + t4 * 4);
#pragma unroll
        for (int jl = 0; jl < 2; jl++) {
            int j = 2 * wv + jl;
            bf16x8 B = *(const bf16x8*)(wfrag + ((q * 8 + j) * 64 + lane) * 4);
            acc[jl] = __builtin_amdgcn_mfma_f32_16x16x32_bf16(A, B, acc[jl], 0, 0, 0);
        }
    }
    float s1[4] = {0.f, 0.f, 0.f, 0.f}, s2[4] = {0.f, 0.f, 0.f, 0.f};
#pragma unroll
    for (int jl = 0; jl < 2; jl++) {
        float bb = bias[16 * (2 * wv + jl) + sub];
#pragma unroll
        for (int r = 0; r < 4; r++) {
            float v = acc[jl][r] + bb;
            acc[jl][r] = v;
            s1[r] += v; s2[r] += v * v;
        }
    }
#pragma unroll
    for (int r = 0; r < 4; r++) {
#pragma unroll
        for (int m = 1; m <= 8; m <<= 1) {
            s1[r] += __shfl_xor(s1[r], m, 64);
            s2[r] += __shfl_xor(s2[r], m, 64);
        }
        if (sub == 0) { lred1[wv][4 * t4 + r] = s1[r]; lred2[wv][4 * t4 + r] = s2[r]; }
    }
    __syncthreads();
    float mu[4], rs[4];
#pragma unroll
    for (int r = 0; r < 4; r++) {
        int n16 = 4 * t4 + r;
        float t1 = lred1[0][n16] + lred1[1][n16] + lred1[2][n16] + lred1[3][n16];
        float t2 = lred2[0][n16] + lred2[1][n16] + lred2[2][n16] + lred2[3][n16];
        mu[r] = t1 * (1.f / DH);
        float var = t2 * (1.f / DH) - mu[r] * mu[r];
        rs[r] = rsqrtf(var + LNEPS);
    }
#pragma unroll
    for (int jl = 0; jl < 2; jl++) {
        int j = 2 * wv + jl;
        float gg = lng[16 * j + sub], be = lnb[16 * j + sub];
#pragma unroll
        for (int r = 0; r < 4; r++) {
            float o = (acc[jl][r] - mu[r]) * rs[r] * gg + be;
            store_dual(dstb, dst8, base + 4 * t4 + r, j, sub, o);
        }
    }
}

template <bool LAST>
__device__ __forceinline__ void body_fused(const u32* __restrict__ srcb,
                                           const u32* __restrict__ src8,
                                           u32* __restrict__ dstb, u32* __restrict__ dst8,
                                           const u32* __restrict__ wfragL,
                                           const float* __restrict__ bias,
                                           const float* __restrict__ lng,
                                           const float* __restrict__ lnb,
                                           const u32* __restrict__ gfrag,
                                           const float* __restrict__ gateb,
                                           float* __restrict__ hh,
                                           unsigned short* __restrict__ acc_g,
                                           const float* __restrict__ sc, int rkj,
                                           const u32* __restrict__ epk,
                                           u32* tile, float (*lred1)[16], float (*lred2)[16],
                                           int wv, int lane, int base, int e0, int e1) {
    int t4 = lane >> 4, sub = lane & 15;
    int row = wv * 4 + t4;

    // prefetch own-node A-frags (block-local, L2-warm) — overlaps gather latency
    bf16x8 Ahc[4];
#pragma unroll
    for (int q = 0; q < 4; q++)
        Ahc[q] = *(const bf16x8*)(srcb + (base + sub) * 64 + q * 16 + t4 * 4);

    // LAST: prefetch epilogue operands (all block-local)
    float hv_p[2][4]; u32 py_p[2][4]; float av_p[2][4];
    if (LAST) {
#pragma unroll
        for (int jl = 0; jl < 2; jl++) {
            int j = 2 * wv + jl;
#pragma unroll
            for (int r = 0; r < 4; r++) {
                int node = base + 4 * t4 + r;
                int fi = node * DH + 16 * j + sub;
                hv_p[jl][r] = hh[fi];
                py_p[jl][r] = dstb[node * 64 + j * 8 + (sub >> 1)];
                av_p[jl][r] = (rkj != 0) ? __uint_as_float((u32)acc_g[fi] << 16) : 0.f;
            }
        }
    }

    gather_row(src8, tile, row, sub, t4 * 16, e0, e1, epk);
    __syncthreads();

    // GEMM1: this wave's 2 output j's only
    f32x4 acc[2];
#pragma unroll
    for (int jl = 0; jl < 2; jl++) acc[jl] = (f32x4){0.f, 0.f, 0.f, 0.f};
#pragma unroll
    for (int q = 0; q < 4; q++) {
        bf16x8 A = *(const bf16x8*)(tile + sub * 68 + q * 16 + t4 * 4);
#pragma unroll
        for (int jl = 0; jl < 2; jl++) {
            int j = 2 * wv + jl;
            bf16x8 B = *(const bf16x8*)(wfragL + ((q * 8 + j) * 64 + lane) * 4);
            acc[jl] = __builtin_amdgcn_mfma_f32_16x16x32_bf16(A, B, acc[jl], 0, 0, 0);
        }
    }

    // bias + partial LN sums -> LDS cross-wave reduce
    float s1[4] = {0.f, 0.f, 0.f, 0.f}, s2[4] = {0.f, 0.f, 0.f, 0.f};
#pragma unroll
    for (int jl = 0; jl < 2; jl++) {
        float bb = bias[16 * (2 * wv + jl) + sub];
#pragma unroll
        for (int r = 0; r < 4; r++) {
            float v = acc[jl][r] + bb;
            acc[jl][r] = v;
            s1[r] += v; s2[r] += v * v;
        }
    }
#pragma unroll
    for (int r = 0; r < 4; r++) {
#pragma unroll
        for (int m = 1; m <= 8; m <<= 1) {
            s1[r] += __shfl_xor(s1[r], m, 64);
            s2[r] += __shfl_xor(s2[r], m, 64);
        }
        if (sub == 0) { lred1[wv][4 * t4 + r] = s1[r]; lred2[wv][4 * t4 + r] = s2[r]; }
    }
    __syncthreads();   // also guarantees all GEMM1 tile reads done
    float mu[4], rs[4];
#pragma unroll
    for (int r = 0; r < 4; r++) {
        int n16 = 4 * t4 + r;
        float t1 = lred1[0][n16] + lred1[1][n16] + lred1[2][n16] + lred1[3][n16];
        float t2 = lred2[0][n16] + lred2[1][n16] + lred2[2][n16] + lred2[3][n16];
        mu[r] = t1 * (1.f / DH);
        float var = t2 * (1.f / DH) - mu[r] * mu[r];
        rs[r] = rsqrtf(var + LNEPS);
    }
#pragma unroll
    for (int jl = 0; jl < 2; jl++) {
        int j = 2 * wv + jl;
        float gg = lng[16 * j + sub], be = lnb[16 * j + sub];
#pragma unroll
        for (int r = 0; r < 4; r++)
            acc[jl][r] = (acc[jl][r] - mu[r]) * rs[r] * gg + be;
    }

    // hn -> tile (A-layout): each wave writes its own 32-col slice (disjoint)
#pragma unroll
    for (int jl = 0; jl < 2; jl++) {
        int j = 2 * wv + jl;
#pragma unroll
        for (int r = 0; r < 4; r++) {
            float o = acc[jl][r];
            float po = __shfl_xor(o, 1, 64);
            if (!(sub & 1)) tile[(4 * t4 + r) * 68 + j * 8 + (sub >> 1)] = packbf(o, po);
        }
    }
    __syncthreads();

    // GEMM2: gate logits (K=256), this wave's 2 j's; hn A-frags read from LDS
    f32x4 ag[2];
#pragma unroll
    for (int jl = 0; jl < 2; jl++) ag[jl] = (f32x4){0.f, 0.f, 0.f, 0.f};
#pragma unroll
    for (int q = 0; q < 8; q++) {
        bf16x8 A = (q < 4) ? Ahc[q]
                           : *(const bf16x8*)(tile + sub * 68 + (q - 4) * 16 + t4 * 4);
#pragma unroll
        for (int jl = 0; jl < 2; jl++) {
            int j = 2 * wv + jl;
            bf16x8 B = *(const bf16x8*)(gfrag + ((q * 8 + j) * 64 + lane) * 4);
            ag[jl] = __builtin_amdgcn_mfma_f32_16x16x32_bf16(A, B, ag[jl], 0, 0, 0);
        }
    }

    // epilogue for own j's
    float dt = 0.f, rw = 0.f;
    if (LAST) { dt = sc[1]; rw = sc[2]; }
#pragma unroll
    for (int jl = 0; jl < 2; jl++) {
        int j = 2 * wv + jl;
        float gbj = gateb[16 * j + sub];
#pragma unroll
        for (int r = 0; r < 4; r++) {
            int node = base + 4 * t4 + r;
            int ui = node * 64 + j * 8 + (sub >> 1);
            float g = sigm(ag[jl][r] + gbj);
            u32 pc = srcb[ui];   // block-local, L1/L2-warm
            float hcv = (sub & 1) ? bfhi(pc) : bflo(pc);
            float o = g * acc[jl][r] + (1.f - g) * hcv;
            if (!LAST) {
                store_dual(dstb, dst8, node, j, sub, o);
            } else {
                float z = fminf(fmaxf(o, -15.f), 15.f);
                float e = __expf(2.f * z);
                float th = (e - 1.f) / (e + 1.f);
                float yv = (sub & 1) ? bfhi(py_p[jl][r]) : bflo(py_p[jl][r]);
                float kk = th + rw * yv;
                float wj = dt * (1.f / 6.f) * ((rkj == 1 || rkj == 2) ? 2.f : 1.f);
                int fi = node * DH + 16 * j + sub;
                float av = wj * kk + av_p[jl][r];
                acc_g[fi] = (unsigned short)f2bf(av);
                float hv = hv_p[jl][r];
                if (rkj < 3) {
                    float c = (rkj == 2) ? dt : 0.5f * dt;
                    store_dual(dstb, dst8, node, j, sub, hv + c * kk);
                } else {
                    float f = hv + av;
                    hh[fi] = f;
                    store_dual(dstb, dst8, node, j, sub, f);
                }
            }
        }
    }
}

// ---------- grid barrier v3: NO acquire-invalidate (cross-block state is sc1-only).
// Arrival = RELEASE add (drains vmcnt, writes back dirty); poll relaxed; exit plain.
__device__ __forceinline__ void pbar(u32* bars, u32 phase) {
    __syncthreads();
    if (threadIdx.x == 0) {
        int grp = blockIdx.x & 7;
        u32 per = (grp < (NCHUNK & 7)) ? (u32)(NCHUNK / 8 + 1) : (u32)(NCHUNK / 8);
        u32 old = __hip_atomic_fetch_add(&bars[grp * 32], 1u, __ATOMIC_RELEASE,
                                         __HIP_MEMORY_SCOPE_AGENT);
        if (old == phase * per - 1u) {     // last arriver of this group
            u32 g = __hip_atomic_fetch_add(&bars[256], 1u, __ATOMIC_RELEASE,
                                           __HIP_MEMORY_SCOPE_AGENT);
            if (g == phase * 8u - 1u)      // last group
                __hip_atomic_store(&bars[288], phase, __ATOMIC_RELEASE,
                                   __HIP_MEMORY_SCOPE_AGENT);
        }
        while (__hip_atomic_load(&bars[288], __ATOMIC_RELAXED, __HIP_MEMORY_SCOPE_AGENT) < phase)
            __builtin_amdgcn_s_sleep(8);
    }
    __syncthreads();
}

// ---------- persistent ODE kernel: 19 steps x 4 RK stages x 3 layers ----------
__global__ __launch_bounds__(256, 5) void k_ode(u32* y, u32* y8, u32* hc, u32* hc8,
                                                u32* hc2, u32* hc28,
                                                const u32* __restrict__ wfrag,
                                                const u32* __restrict__ gfrag,
                                                const float* __restrict__ gcnb,
                                                const float* __restrict__ lng,
                                                const float* __restrict__ lnb,
                                                const float* __restrict__ gateb,
                                                float* __restrict__ hh,
                                                unsigned short* __restrict__ accg,
                                                const float* __restrict__ sc,
                                                const int* __restrict__ offs,
                                                const u32* __restrict__ epk,
                                                u32* bars) {
    __shared__ u32 tile[16 * 68];
    __shared__ float lred1[4][16], lred2[4][16];
    int wv = threadIdx.x >> 6, lane = threadIdx.x & 63;
    int base = blockIdx.x * 16;
    int t4 = lane >> 4;
    int row = wv * 4 + t4;
    int e0 = offs[base + row], e1 = offs[base + row + 1];  // invariant across phases

    const int LSZ = 32 * 64 * 4;
    u32 phase = 0;
    for (int s = 0; s < TSTEPS - 1; s++) {
        for (int j = 0; j < 4; j++) {
            body_aggmm(y8, hc, hc8, wfrag, gcnb, lng, lnb, epk,
                       tile, lred1, lred2, wv, lane, base, e0, e1);
            pbar(bars, ++phase);
            body_fused<false>(hc, hc8, hc2, hc28, wfrag + LSZ, gcnb + DH, lng + DH, lnb + DH,
                              gfrag, gateb, nullptr, nullptr, sc, j, epk,
                              tile, lred1, lred2, wv, lane, base, e0, e1);
            pbar(bars, ++phase);
            body_fused<true>(hc2, hc28, y, y8, wfrag + 2 * LSZ, gcnb + 2 * DH, lng + 2 * DH,
                             lnb + 2 * DH, gfrag, gateb, hh, accg, sc, j, epk,
                             tile, lred1, lred2, wv, lane, base, e0, e1);
            if (s != TSTEPS - 2 || j != 3)   // last phase: kernel end is the barrier
                pbar(bars, ++phase);
        }
    }
}

// ---------- output projection + LN + global mean (known-good) ----------
__global__ __launch_bounds__(1024) void k_outproj(const float* __restrict__ hh, const u32* wopk,
                                                  const float* bo, const float* g, const float* b,
                                                  float* oacc) {
    __shared__ u32 Wl[64 * DH];
    __shared__ float red[DH];
    for (int i = threadIdx.x; i < 64 * DH; i += 1024) Wl[i] = wopk[i];
    if (threadIdx.x < DH) red[threadIdx.x] = 0.f;
    __syncthreads();
    int wv = threadIdx.x >> 6, t = threadIdx.x & 63;
    int n = blockIdx.x * 16 + wv;
    if (n < NN) {
        float2 hv = *(const float2*)&hh[n * DH + 2 * t];
        float h0 = hv.x, h1 = hv.y;
        float2 bb = *(const float2*)&bo[2 * t];
        float y0 = bb.x, y1 = bb.y;
#pragma unroll
        for (int k2 = 0; k2 < 64; k2++) {
            float a0 = __shfl(h0, k2, 64), a1 = __shfl(h1, k2, 64);
            uint2 wq = *(const uint2*)&Wl[k2 * DH + 2 * t];
            y0 += a0 * bflo(wq.x) + a1 * bfhi(wq.x);
            y1 += a0 * bflo(wq.y) + a1 * bfhi(wq.y);
        }
        float mu = wredsum(y0 + y1) * (1.f / DH);
        float d0 = y0 - mu, d1 = y1 - mu;
        float var = wredsum(d0 * d0 + d1 * d1) * (1.f / DH);
        float r = rsqrtf(var + LNEPS);
        float2 gg = *(const float2*)&g[2 * t], lb = *(const float2*)&b[2 * t];
        atomicAdd(&red[2 * t], d0 * r * gg.x + lb.x);
        atomicAdd(&red[2 * t + 1], d1 * r * gg.y + lb.y);
    }
    __syncthreads();
    if (threadIdx.x < DH) atomicAdd(&oacc[threadIdx.x], red[threadIdx.x]);
}

__global__ void k_final(const float* oacc, float* out) {
    int t = threadIdx.x;
    if (t < DH) out[t] = oacc[t] * (1.f / (float)NN);
}

// ---------- host ----------
extern "C" void kernel_launch(void* const* d_in, const int* in_sizes, int n_in,
                              void* d_out, int out_size, void* d_ws, size_t ws_size,
                              hipStream_t stream) {
    const float* x     = (const float*)d_in[0];
    const int*   ei    = (const int*)d_in[1];
    const float* Wi    = (const float*)d_in[2];
    const float* bi    = (const float*)d_in[3];
    const float* ling  = (const float*)d_in[4];
    const float* linb  = (const float*)d_in[5];
    const float* meth  = (const float*)d_in[6];
    const float* hist  = (const float*)d_in[7];
    const float* gcnw  = (const float*)d_in[8];
    const float* gcnb  = (const float*)d_in[9];
    const float* lng   = (const float*)d_in[10];
    const float* lnb   = (const float*)d_in[11];
    const float* gatew = (const float*)d_in[12];
    const float* gateb = (const float*)d_in[13];
    const float* resw  = (const float*)d_in[14];
    const float* logd  = (const float*)d_in[15];
    const float* Wo    = (const float*)d_in[16];
    const float* bo    = (const float*)d_in[17];
    const float* loutg = (const float*)d_in[18];
    const float* loutb = (const float*)d_in[19];

    char* wsb = (char*)d_ws;
    size_t off = 0;
    auto alloc = [&](size_t bytes) -> void* {
        void* p = wsb + off;
        off += (bytes + 255) & ~(size_t)255;
        return p;
    };
    float* sc     = (float*)alloc(32);
    u32*   bars   = (u32*)alloc(512 * 4);   // padded barrier counters
    int*   deg    = (int*)alloc(NN * 4);
    int*   offs   = (int*)alloc((NN + 1) * 4);
    int*   cursor = (int*)alloc(NN * 4);
    float* dis    = (float*)alloc(NN * 4);
    u32*   epk    = (u32*)alloc(EE * 4);
    u32*   wfrag  = (u32*)alloc(3 * 32 * 64 * 4 * 4);
    u32*   gfrag  = (u32*)alloc(64 * 64 * 4 * 4);
    u32*   wopk   = (u32*)alloc(64 * DH * 4);
    u32*   y      = (u32*)alloc((size_t)NN * 64 * 4);   // bf16 rows (block-local)
    u32*   hc     = (u32*)alloc((size_t)NN * 64 * 4);
    u32*   hc2    = (u32*)alloc((size_t)NN * 64 * 4);
    u32*   y8     = (u32*)alloc((size_t)NN * 32 * 4);   // fp8 rows (cross-block, sc1)
    u32*   hc8    = (u32*)alloc((size_t)NN * 32 * 4);
    u32*   hc28   = (u32*)alloc((size_t)NN * 32 * 4);
    float* hh     = (float*)alloc((size_t)NN * DH * 4);
    unsigned short* accg = (unsigned short*)alloc((size_t)NN * DH * 2);
    float* oacc   = (float*)alloc(DH * 4);

    const int* row = ei;
    const int* col = ei + EE;

    k_init<<<(NN + 255) / 256, 256, 0, stream>>>(deg, oacc, bars);
    k_scalars<<<1, 1, 0, stream>>>(meth, hist, logd, resw, sc);
    k_deg<<<(EE + 255) / 256, 256, 0, stream>>>(col, deg);
    k_scan<<<1, 1024, 0, stream>>>(deg, offs, cursor, dis);
    k_scatter<<<(EE + 255) / 256, 256, 0, stream>>>(row, col, cursor, dis, epk);
    k_pack<<<(6144 + 4096 + 8192 + 255) / 256, 256, 0, stream>>>(gcnw, gatew, Wo, wfrag, gfrag, wopk);

    const int GB1 = (NN + 15) / 16;
    k_inproj<<<GB1, 1024, 0, stream>>>(x, Wi, bi, ling, linb, sc, y, y8, hh);

    // persistent: 1250 blocks x 256 thr; launch_bounds(256,5) -> 5 blocks/CU
    // -> capacity 1280 >= 1250, all resident (required for the grid barrier)
    k_ode<<<NCHUNK, 256, 0, stream>>>(y, y8, hc, hc8, hc2, hc28, wfrag, gfrag,
                                      gcnb, lng, lnb, gateb, hh, accg, sc, offs, epk, bars);

    k_outproj<<<GB1, 1024, 0, stream>>>(hh, wopk, bo, loutg, loutb, oacc);
    k_final<<<1, 128, 0, stream>>>(oacc, (float*)d_out);
}

// Round 10
// 7159.279 us; speedup vs baseline: 4.2351x; 3.9295x over previous
//
#include <hip/hip_runtime.h>

typedef unsigned int u32;
using bf16x8 = __attribute__((ext_vector_type(8))) short;
using f32x4  = __attribute__((ext_vector_type(4))) float;
using f32x2  = __attribute__((ext_vector_type(2))) float;

#define NN 20000
#define EE 320000
#define DH 128
#define DIN 64
#define TSTEPS 20
#define LNEPS 1e-5f
#define NCHUNK 1250   // 20000 / 16-node chunks; 1 block (4 waves) per chunk

// ---------- helpers ----------
__device__ __forceinline__ u32 f2bf(float f) {
    u32 x = __float_as_uint(f);
    return (x + 0x7fffu + ((x >> 16) & 1u)) >> 16;   // RNE to bf16 bits
}
__device__ __forceinline__ float bflo(u32 p) { return __uint_as_float(p << 16); }
__device__ __forceinline__ float bfhi(u32 p) { return __uint_as_float(p & 0xffff0000u); }
__device__ __forceinline__ u32 packbf(float a, float b) { return f2bf(a) | (f2bf(b) << 16); }
__device__ __forceinline__ float wredsum(float v) {
#pragma unroll
    for (int m = 32; m >= 1; m >>= 1) v += __shfl_xor(v, m, 64);
    return v;
}
__device__ __forceinline__ float sigm(float x) { return 1.f / (1.f + __expf(-x)); }

// decode 8 fp8(e4m3) + weighted accumulate
__device__ __forceinline__ void accum8_fp8(float* a, uint2 q, float w) {
    f32x2 c01 = __builtin_amdgcn_cvt_pk_f32_fp8((int)q.x, false);
    f32x2 c23 = __builtin_amdgcn_cvt_pk_f32_fp8((int)q.x, true);
    f32x2 c45 = __builtin_amdgcn_cvt_pk_f32_fp8((int)q.y, false);
    f32x2 c67 = __builtin_amdgcn_cvt_pk_f32_fp8((int)q.y, true);
    a[0] += w * c01[0]; a[1] += w * c01[1];
    a[2] += w * c23[0]; a[3] += w * c23[1];
    a[4] += w * c45[0]; a[5] += w * c45[1];
    a[6] += w * c67[0]; a[7] += w * c67[1];
}

// dual store: bf16 row (node-local consumers) + fp8 row (gather consumers)
__device__ __forceinline__ void store_dual(u32* dstb, u32* dst8, int node, int j, int sub, float o) {
    float po = __shfl_xor(o, 1, 64);
    if (!(sub & 1)) dstb[node * 64 + j * 8 + (sub >> 1)] = packbf(o, po);
    int pk = __builtin_amdgcn_cvt_pk_fp8_f32(o, po, 0, false);
    int pk2 = __shfl_xor(pk, 2, 64);
    if (!(sub & 3)) dst8[node * 32 + j * 4 + (sub >> 2)] = (u32)(pk & 0xffff) | ((u32)pk2 << 16);
}

// ---------- setup kernels ----------
__global__ void k_init(int* deg, float* oacc) {
    int i = blockIdx.x * blockDim.x + threadIdx.x;
    if (i < NN) deg[i] = 0;
    if (i < DH) oacc[i] = 0.f;
}

__global__ void k_scalars(const float* meth, const float* hist, const float* logd,
                          const float* resw, float* sc) {
    float msum = 0.f;
    for (int j = 0; j < DH; j++) msum += sigm(meth[j]);
    float msil = msum * (1.f / DH);
    float h0 = sigm(hist[0]), h1 = sigm(hist[1]), h2 = sigm(hist[2]), h3 = sigm(hist[3]);
    float act = 0.5f * (h0 + h2), rep = 0.5f * (h1 + h3);
    float access = fminf(fmaxf(act - rep + 0.5f, 0.f), 1.f);
    sc[0] = access * (1.f - msil);
    float depth = fminf(fmaxf(__expf(logd[0]), 0.1f), 3.f);
    sc[1] = depth / (float)(TSTEPS - 1);
    sc[2] = resw[0];
}

__global__ void k_deg(const int* col, int* deg) {
    int e = blockIdx.x * blockDim.x + threadIdx.x;
    if (e < EE) atomicAdd(&deg[col[e]], 1);
}

__global__ __launch_bounds__(1024) void k_scan(const int* deg, int* offs, int* cursor, float* dis) {
    __shared__ int part[1024];
    const int CH = (NN + 1023) / 1024;
    int t = threadIdx.x;
    int base = t * CH;
    int s = 0;
    for (int k = 0; k < CH; k++) { int i = base + k; if (i < NN) s += deg[i]; }
    part[t] = s;
    __syncthreads();
    for (int off = 1; off < 1024; off <<= 1) {
        int v = part[t];
        int add = (t >= off) ? part[t - off] : 0;
        __syncthreads();
        part[t] = v + add;
        __syncthreads();
    }
    int run = part[t] - s;
    for (int k = 0; k < CH; k++) {
        int i = base + k;
        if (i < NN) {
            offs[i] = run; cursor[i] = run;
            int d = deg[i];
            run += d;
            dis[i] = (d > 0) ? rsqrtf((float)d) : 0.f;
        }
    }
    if (t == 1023) offs[NN] = run;
}

// edge record: (bf16 norm << 16) | src  (src < 20000 fits 16 bits)
__global__ void k_scatter(const int* row, const int* col, int* cursor, const float* dis,
                          u32* epk) {
    int e = blockIdx.x * blockDim.x + threadIdx.x;
    if (e < EE) {
        int c = col[e], r = row[e];
        int pos = atomicAdd(&cursor[c], 1);
        epk[pos] = (f2bf(dis[r] * dis[c]) << 16) | (u32)r;
    }
}

// ---------- fragment-order weight packing (known-good) ----------
__global__ void k_pack(const float* gcnw, const float* gatew, const float* Wo,
                       u32* wfrag, u32* gfrag, u32* wopk) {
    int tid = blockIdx.x * blockDim.x + threadIdx.x;
    if (tid < 6144) {                       // 3 layers * 4q * 8j * 64 lanes
        int lane = tid & 63, rem = tid >> 6;
        int j = rem & 7; rem >>= 3;
        int q = rem & 3; int l = rem >> 2;
        const float* W = gcnw + l * DH * DH;
        int r0 = 32 * q + 8 * (lane >> 4);
        int c  = 16 * j + (lane & 15);
        u32* o = wfrag + tid * 4;
#pragma unroll
        for (int p = 0; p < 4; p++)
            o[p] = packbf(W[(r0 + 2 * p) * DH + c], W[(r0 + 2 * p + 1) * DH + c]);
    } else if (tid < 6144 + 4096) {         // 8q * 8j * 64 lanes (gate 256x128)
        int t = tid - 6144;
        int lane = t & 63, rem = t >> 6;
        int j = rem & 7, q = rem >> 3;
        int r0 = 32 * q + 8 * (lane >> 4);
        int c  = 16 * j + (lane & 15);
        u32* o = gfrag + t * 4;
#pragma unroll
        for (int p = 0; p < 4; p++)
            o[p] = packbf(gatew[(r0 + 2 * p) * DH + c], gatew[(r0 + 2 * p + 1) * DH + c]);
    } else if (tid < 6144 + 4096 + 8192) {  // 64*128 u32 (Wo pair-packed)
        int t = tid - 10240;
        int k2 = t / DH, j = t % DH;
        wopk[t] = packbf(Wo[(2 * k2) * DH + j], Wo[(2 * k2 + 1) * DH + j]);
    }
}

// ---------- input projection: writes bf16 y, fp8 y8, fp32 hh ----------
__global__ __launch_bounds__(1024) void k_inproj(const float* x, const float* Wi, const float* bi,
                                                 const float* g, const float* b, const float* sc,
                                                 u32* y, u32* y8, float* hh) {
    __shared__ float Wl[DIN * DH];
    for (int i = threadIdx.x; i < DIN * DH; i += 1024) Wl[i] = Wi[i];
    __syncthreads();
    int wv = threadIdx.x >> 6, t = threadIdx.x & 63;
    int n = blockIdx.x * 16 + wv;
    if (n >= NN) return;
    float xv = x[n * DIN + t];
    float2 bb = *(const float2*)&bi[2 * t];
    float y0 = bb.x, y1 = bb.y;
#pragma unroll
    for (int k = 0; k < DIN; k++) {
        float a = __shfl(xv, k, 64);
        float2 w = *(const float2*)&Wl[k * DH + 2 * t];
        y0 += a * w.x; y1 += a * w.y;
    }
    float mu = wredsum(y0 + y1) * (1.f / DH);
    float d0 = y0 - mu, d1 = y1 - mu;
    float var = wredsum(d0 * d0 + d1 * d1) * (1.f / DH);
    float r = rsqrtf(var + LNEPS);
    float2 gg = *(const float2*)&g[2 * t], lb = *(const float2*)&b[2 * t];
    float scale = sc[0];
    float v0 = fmaxf(d0 * r * gg.x + lb.x, 0.f) * scale;
    float v1 = fmaxf(d1 * r * gg.y + lb.y, 0.f) * scale;
    y[n * 64 + t] = packbf(v0, v1);
    *(float2*)&hh[n * DH + 2 * t] = make_float2(v0, v1);
    int pk = __builtin_amdgcn_cvt_pk_fp8_f32(v0, v1, 0, false);
    int pk2 = __shfl_xor(pk, 1, 64);
    if (!(t & 1)) y8[n * 32 + (t >> 1)] = (u32)(pk & 0xffff) | ((u32)pk2 << 16);
}

// ---------- gather ONE row per quarter-wave, ALL 16 edge-loads in flight ----------
// Lanes beyond cc hold epk=0 -> dummy loads of node 0 (L1-resident), weight 0.
__device__ __forceinline__ void gather_row(const u32* __restrict__ src8, u32* tile,
                                           int row, int sub, int qb, int e0, int e1,
                                           const u32* __restrict__ epk) {
    float a[8] = {0.f, 0.f, 0.f, 0.f, 0.f, 0.f, 0.f, 0.f};
    for (int eb = e0; eb < e1; eb += 16) {
        int cc = min(16, e1 - eb);
        u32 p = 0;
        if (sub < cc) p = epk[eb + sub];
        u32 pe[16]; uint2 q[16];
#pragma unroll
        for (int u = 0; u < 16; u++) pe[u] = (u32)__shfl((int)p, qb + u, 64);
#pragma unroll
        for (int u = 0; u < 16; u++)
            q[u] = *(const uint2*)(src8 + (pe[u] & 0xffffu) * 32 + sub * 2);
#pragma unroll
        for (int u = 0; u < 16; u++)
            accum8_fp8(a, q[u], __uint_as_float(pe[u] & 0xffff0000u));
    }
    uint4 v;
    v.x = packbf(a[0], a[1]); v.y = packbf(a[2], a[3]);
    v.z = packbf(a[4], a[5]); v.w = packbf(a[6], a[7]);
    *(uint4*)(tile + row * 68 + sub * 4) = v;
}

// ---------- layer 0: gather + GEMM + LN, j-split across waves ----------
__global__ __launch_bounds__(256, 5) void k_aggmm(const u32* __restrict__ src8,
                                                  u32* __restrict__ dstb, u32* __restrict__ dst8,
                                                  const u32* __restrict__ wfrag,
                                                  const float* __restrict__ bias,
                                                  const float* __restrict__ lng,
                                                  const float* __restrict__ lnb,
                                                  const int* __restrict__ offs,
                                                  const u32* __restrict__ epk) {
    __shared__ u32 tile[16 * 68];
    __shared__ float lred1[4][16], lred2[4][16];
    int wv = threadIdx.x >> 6, lane = threadIdx.x & 63;
    int base = blockIdx.x * 16;
    int t4 = lane >> 4, sub = lane & 15;
    int row = wv * 4 + t4;
    int e0 = offs[base + row], e1 = offs[base + row + 1];
    gather_row(src8, tile, row, sub, t4 * 16, e0, e1, epk);
    __syncthreads();

    // GEMM1: this wave's 2 output j's only
    f32x4 acc[2];
#pragma unroll
    for (int jl = 0; jl < 2; jl++) acc[jl] = (f32x4){0.f, 0.f, 0.f, 0.f};
#pragma unroll
    for (int q = 0; q < 4; q++) {
        bf16x8 A = *(const bf16x8*)(tile + sub * 68 + q * 16 + t4 * 4);
#pragma unroll
        for (int jl = 0; jl < 2; jl++) {
            int j = 2 * wv + jl;
            bf16x8 B = *(const bf16x8*)(wfrag + ((q * 8 + j) * 64 + lane) * 4);
            acc[jl] = __builtin_amdgcn_mfma_f32_16x16x32_bf16(A, B, acc[jl], 0, 0, 0);
        }
    }
    // bias + partial LN sums (32 cols per wave) -> LDS reduce
    float s1[4] = {0.f, 0.f, 0.f, 0.f}, s2[4] = {0.f, 0.f, 0.f, 0.f};
#pragma unroll
    for (int jl = 0; jl < 2; jl++) {
        float bb = bias[16 * (2 * wv + jl) + sub];
#pragma unroll
        for (int r = 0; r < 4; r++) {
            float v = acc[jl][r] + bb;
            acc[jl][r] = v;
            s1[r] += v; s2[r] += v * v;
        }
    }
#pragma unroll
    for (int r = 0; r < 4; r++) {
#pragma unroll
        for (int m = 1; m <= 8; m <<= 1) {
            s1[r] += __shfl_xor(s1[r], m, 64);
            s2[r] += __shfl_xor(s2[r], m, 64);
        }
        if (sub == 0) { lred1[wv][4 * t4 + r] = s1[r]; lred2[wv][4 * t4 + r] = s2[r]; }
    }
    __syncthreads();
    float mu[4], rs[4];
#pragma unroll
    for (int r = 0; r < 4; r++) {
        int n16 = 4 * t4 + r;
        float t1 = lred1[0][n16] + lred1[1][n16] + lred1[2][n16] + lred1[3][n16];
        float t2 = lred2[0][n16] + lred2[1][n16] + lred2[2][n16] + lred2[3][n16];
        mu[r] = t1 * (1.f / DH);
        float var = t2 * (1.f / DH) - mu[r] * mu[r];
        rs[r] = rsqrtf(var + LNEPS);
    }
#pragma unroll
    for (int jl = 0; jl < 2; jl++) {
        int j = 2 * wv + jl;
        float gg = lng[16 * j + sub], be = lnb[16 * j + sub];
#pragma unroll
        for (int r = 0; r < 4; r++) {
            float o = (acc[jl][r] - mu[r]) * rs[r] * gg + be;
            store_dual(dstb, dst8, base + 4 * t4 + r, j, sub, o);
        }
    }
}

// ---------- fused: gather + GEMM + LN + gate GEMM + blend (+ RK4), j-split ----------
template <bool LAST>
__global__ __launch_bounds__(256, 5) void k_fused(const u32* __restrict__ srcb,
                                                  const u32* __restrict__ src8,
                                                  u32* __restrict__ dstb, u32* __restrict__ dst8,
                                                  const u32* __restrict__ wfragL,
                                                  const float* __restrict__ bias,
                                                  const float* __restrict__ lng,
                                                  const float* __restrict__ lnb,
                                                  const u32* __restrict__ gfrag,
                                                  const float* __restrict__ gateb,
                                                  float* __restrict__ hh,
                                                  unsigned short* __restrict__ acc_g,
                                                  const float* __restrict__ sc, int rkj,
                                                  const int* __restrict__ offs,
                                                  const u32* __restrict__ epk) {
    __shared__ u32 tile[16 * 68];
    __shared__ float lred1[4][16], lred2[4][16];
    int wv = threadIdx.x >> 6, lane = threadIdx.x & 63;
    int base = blockIdx.x * 16;
    int t4 = lane >> 4, sub = lane & 15;
    int row = wv * 4 + t4;
    int e0 = offs[base + row], e1 = offs[base + row + 1];

    // prefetch own-node A-frags (gate first half) — overlaps gather latency
    bf16x8 Ahc[4];
#pragma unroll
    for (int q = 0; q < 4; q++)
        Ahc[q] = *(const bf16x8*)(srcb + (base + sub) * 64 + q * 16 + t4 * 4);

    // LAST: prefetch cold epilogue operands (hh, residual row, RK4 acc)
    float hv_p[2][4]; u32 py_p[2][4]; float av_p[2][4];
    if (LAST) {
#pragma unroll
        for (int jl = 0; jl < 2; jl++) {
            int j = 2 * wv + jl;
#pragma unroll
            for (int r = 0; r < 4; r++) {
                int node = base + 4 * t4 + r;
                int fi = node * DH + 16 * j + sub;
                hv_p[jl][r] = hh[fi];
                py_p[jl][r] = dstb[node * 64 + j * 8 + (sub >> 1)];
                av_p[jl][r] = (rkj != 0) ? __uint_as_float((u32)acc_g[fi] << 16) : 0.f;
            }
        }
    }

    gather_row(src8, tile, row, sub, t4 * 16, e0, e1, epk);
    __syncthreads();

    // GEMM1: this wave's 2 output j's only
    f32x4 acc[2];
#pragma unroll
    for (int jl = 0; jl < 2; jl++) acc[jl] = (f32x4){0.f, 0.f, 0.f, 0.f};
#pragma unroll
    for (int q = 0; q < 4; q++) {
        bf16x8 A = *(const bf16x8*)(tile + sub * 68 + q * 16 + t4 * 4);
#pragma unroll
        for (int jl = 0; jl < 2; jl++) {
            int j = 2 * wv + jl;
            bf16x8 B = *(const bf16x8*)(wfragL + ((q * 8 + j) * 64 + lane) * 4);
            acc[jl] = __builtin_amdgcn_mfma_f32_16x16x32_bf16(A, B, acc[jl], 0, 0, 0);
        }
    }

    // bias + partial LN sums -> LDS cross-wave reduce
    float s1[4] = {0.f, 0.f, 0.f, 0.f}, s2[4] = {0.f, 0.f, 0.f, 0.f};
#pragma unroll
    for (int jl = 0; jl < 2; jl++) {
        float bb = bias[16 * (2 * wv + jl) + sub];
#pragma unroll
        for (int r = 0; r < 4; r++) {
            float v = acc[jl][r] + bb;
            acc[jl][r] = v;
            s1[r] += v; s2[r] += v * v;
        }
    }
#pragma unroll
    for (int r = 0; r < 4; r++) {
#pragma unroll
        for (int m = 1; m <= 8; m <<= 1) {
            s1[r] += __shfl_xor(s1[r], m, 64);
            s2[r] += __shfl_xor(s2[r], m, 64);
        }
        if (sub == 0) { lred1[wv][4 * t4 + r] = s1[r]; lred2[wv][4 * t4 + r] = s2[r]; }
    }
    __syncthreads();   // also guarantees all GEMM1 tile reads done
    float mu[4], rs[4];
#pragma unroll
    for (int r = 0; r < 4; r++) {
        int n16 = 4 * t4 + r;
        float t1 = lred1[0][n16] + lred1[1][n16] + lred1[2][n16] + lred1[3][n16];
        float t2 = lred2[0][n16] + lred2[1][n16] + lred2[2][n16] + lred2[3][n16];
        mu[r] = t1 * (1.f / DH);
        float var = t2 * (1.f / DH) - mu[r] * mu[r];
        rs[r] = rsqrtf(var + LNEPS);
    }
#pragma unroll
    for (int jl = 0; jl < 2; jl++) {
        int j = 2 * wv + jl;
        float gg = lng[16 * j + sub], be = lnb[16 * j + sub];
#pragma unroll
        for (int r = 0; r < 4; r++)
            acc[jl][r] = (acc[jl][r] - mu[r]) * rs[r] * gg + be;
    }

    // hn -> tile (A-layout): each wave writes its own 32-col slice (disjoint)
#pragma unroll
    for (int jl = 0; jl < 2; jl++) {
        int j = 2 * wv + jl;
#pragma unroll
        for (int r = 0; r < 4; r++) {
            float o = acc[jl][r];
            float po = __shfl_xor(o, 1, 64);
            if (!(sub & 1)) tile[(4 * t4 + r) * 68 + j * 8 + (sub >> 1)] = packbf(o, po);
        }
    }
    __syncthreads();

    // GEMM2: gate logits (K=256), this wave's 2 j's; hn A-frags read from LDS
    f32x4 ag[2];
#pragma unroll
    for (int jl = 0; jl < 2; jl++) ag[jl] = (f32x4){0.f, 0.f, 0.f, 0.f};
#pragma unroll
    for (int q = 0; q < 8; q++) {
        bf16x8 A = (q < 4) ? Ahc[q]
                           : *(const bf16x8*)(tile + sub * 68 + (q - 4) * 16 + t4 * 4);
#pragma unroll
        for (int jl = 0; jl < 2; jl++) {
            int j = 2 * wv + jl;
            bf16x8 B = *(const bf16x8*)(gfrag + ((q * 8 + j) * 64 + lane) * 4);
            ag[jl] = __builtin_amdgcn_mfma_f32_16x16x32_bf16(A, B, ag[jl], 0, 0, 0);
        }
    }

    // epilogue for own j's
    float dt = 0.f, rw = 0.f;
    if (LAST) { dt = sc[1]; rw = sc[2]; }
#pragma unroll
    for (int jl = 0; jl < 2; jl++) {
        int j = 2 * wv + jl;
        float gbj = gateb[16 * j + sub];
#pragma unroll
        for (int r = 0; r < 4; r++) {
            int node = base + 4 * t4 + r;
            int ui = node * 64 + j * 8 + (sub >> 1);
            float g = sigm(ag[jl][r] + gbj);
            u32 pc = srcb[ui];   // L1-warm (same rows as Ahc)
            float hcv = (sub & 1) ? bfhi(pc) : bflo(pc);
            float o = g * acc[jl][r] + (1.f - g) * hcv;
            if (!LAST) {
                store_dual(dstb, dst8, node, j, sub, o);
            } else {
                float z = fminf(fmaxf(o, -15.f), 15.f);
                float e = __expf(2.f * z);
                float th = (e - 1.f) / (e + 1.f);
                float yv = (sub & 1) ? bfhi(py_p[jl][r]) : bflo(py_p[jl][r]);
                float kk = th + rw * yv;
                float wj = dt * (1.f / 6.f) * ((rkj == 1 || rkj == 2) ? 2.f : 1.f);
                int fi = node * DH + 16 * j + sub;
                float av = wj * kk + av_p[jl][r];
                acc_g[fi] = (unsigned short)f2bf(av);
                float hv = hv_p[jl][r];
                if (rkj < 3) {
                    float c = (rkj == 2) ? dt : 0.5f * dt;
                    store_dual(dstb, dst8, node, j, sub, hv + c * kk);
                } else {
                    float f = hv + av;
                    hh[fi] = f;
                    store_dual(dstb, dst8, node, j, sub, f);
                }
            }
        }
    }
}

// ---------- output projection + LN + global mean (known-good) ----------
__global__ __launch_bounds__(1024) void k_outproj(const float* __restrict__ hh, const u32* wopk,
                                                  const float* bo, const float* g, const float* b,
                                                  float* oacc) {
    __shared__ u32 Wl[64 * DH];
    __shared__ float red[DH];
    for (int i = threadIdx.x; i < 64 * DH; i += 1024) Wl[i] = wopk[i];
    if (threadIdx.x < DH) red[threadIdx.x] = 0.f;
    __syncthreads();
    int wv = threadIdx.x >> 6, t = threadIdx.x & 63;
    int n = blockIdx.x * 16 + wv;
    if (n < NN) {
        float2 hv = *(const float2*)&hh[n * DH + 2 * t];
        float h0 = hv.x, h1 = hv.y;
        float2 bb = *(const float2*)&bo[2 * t];
        float y0 = bb.x, y1 = bb.y;
#pragma unroll
        for (int k2 = 0; k2 < 64; k2++) {
            float a0 = __shfl(h0, k2, 64), a1 = __shfl(h1, k2, 64);
            uint2 wq = *(const uint2*)&Wl[k2 * DH + 2 * t];
            y0 += a0 * bflo(wq.x) + a1 * bfhi(wq.x);
            y1 += a0 * bflo(wq.y) + a1 * bfhi(wq.y);
        }
        float mu = wredsum(y0 + y1) * (1.f / DH);
        float d0 = y0 - mu, d1 = y1 - mu;
        float var = wredsum(d0 * d0 + d1 * d1) * (1.f / DH);
        float r = rsqrtf(var + LNEPS);
        float2 gg = *(const float2*)&g[2 * t], lb = *(const float2*)&b[2 * t];
        atomicAdd(&red[2 * t], d0 * r * gg.x + lb.x);
        atomicAdd(&red[2 * t + 1], d1 * r * gg.y + lb.y);
    }
    __syncthreads();
    if (threadIdx.x < DH) atomicAdd(&oacc[threadIdx.x], red[threadIdx.x]);
}

__global__ void k_final(const float* oacc, float* out) {
    int t = threadIdx.x;
    if (t < DH) out[t] = oacc[t] * (1.f / (float)NN);
}

// ---------- host ----------
extern "C" void kernel_launch(void* const* d_in, const int* in_sizes, int n_in,
                              void* d_out, int out_size, void* d_ws, size_t ws_size,
                              hipStream_t stream) {
    const float* x     = (const float*)d_in[0];
    const int*   ei    = (const int*)d_in[1];
    const float* Wi    = (const float*)d_in[2];
    const float* bi    = (const float*)d_in[3];
    const float* ling  = (const float*)d_in[4];
    const float* linb  = (const float*)d_in[5];
    const float* meth  = (const float*)d_in[6];
    const float* hist  = (const float*)d_in[7];
    const float* gcnw  = (const float*)d_in[8];
    const float* gcnb  = (const float*)d_in[9];
    const float* lng   = (const float*)d_in[10];
    const float* lnb   = (const float*)d_in[11];
    const float* gatew = (const float*)d_in[12];
    const float* gateb = (const float*)d_in[13];
    const float* resw  = (const float*)d_in[14];
    const float* logd  = (const float*)d_in[15];
    const float* Wo    = (const float*)d_in[16];
    const float* bo    = (const float*)d_in[17];
    const float* loutg = (const float*)d_in[18];
    const float* loutb = (const float*)d_in[19];

    char* wsb = (char*)d_ws;
    size_t off = 0;
    auto alloc = [&](size_t bytes) -> void* {
        void* p = wsb + off;
        off += (bytes + 255) & ~(size_t)255;
        return p;
    };
    float* sc     = (float*)alloc(32);
    int*   deg    = (int*)alloc(NN * 4);
    int*   offs   = (int*)alloc((NN + 1) * 4);
    int*   cursor = (int*)alloc(NN * 4);
    float* dis    = (float*)alloc(NN * 4);
    u32*   epk    = (u32*)alloc(EE * 4);
    u32*   wfrag  = (u32*)alloc(3 * 32 * 64 * 4 * 4);
    u32*   gfrag  = (u32*)alloc(64 * 64 * 4 * 4);
    u32*   wopk   = (u32*)alloc(64 * DH * 4);
    u32*   y      = (u32*)alloc((size_t)NN * 64 * 4);   // bf16 rows
    u32*   hc     = (u32*)alloc((size_t)NN * 64 * 4);
    u32*   hc2    = (u32*)alloc((size_t)NN * 64 * 4);
    u32*   y8     = (u32*)alloc((size_t)NN * 32 * 4);   // fp8 rows (gather)
    u32*   hc8    = (u32*)alloc((size_t)NN * 32 * 4);
    u32*   hc28   = (u32*)alloc((size_t)NN * 32 * 4);
    float* hh     = (float*)alloc((size_t)NN * DH * 4);
    unsigned short* accg = (unsigned short*)alloc((size_t)NN * DH * 2);
    float* oacc   = (float*)alloc(DH * 4);

    const int* row = ei;
    const int* col = ei + EE;

    k_init<<<(NN + 255) / 256, 256, 0, stream>>>(deg, oacc);
    k_scalars<<<1, 1, 0, stream>>>(meth, hist, logd, resw, sc);
    k_deg<<<(EE + 255) / 256, 256, 0, stream>>>(col, deg);
    k_scan<<<1, 1024, 0, stream>>>(deg, offs, cursor, dis);
    k_scatter<<<(EE + 255) / 256, 256, 0, stream>>>(row, col, cursor, dis, epk);
    k_pack<<<(6144 + 4096 + 8192 + 255) / 256, 256, 0, stream>>>(gcnw, gatew, Wo, wfrag, gfrag, wopk);

    const int GB1 = (NN + 15) / 16;
    k_inproj<<<GB1, 1024, 0, stream>>>(x, Wi, bi, ling, linb, sc, y, y8, hh);

    const int LSZ = 32 * 64 * 4;      // u32 per layer of wfrag
    for (int s = 0; s < TSTEPS - 1; s++) {
        for (int j = 0; j < 4; j++) {
            // layer 0: gather y8 -> hc (+hc8)
            k_aggmm<<<NCHUNK, 256, 0, stream>>>(y8, hc, hc8, wfrag, gcnb, lng, lnb, offs, epk);
            // layer 1 + gate: gather hc8, node-local hc -> hc2 (+hc28)
            k_fused<false><<<NCHUNK, 256, 0, stream>>>(hc, hc8, hc2, hc28, wfrag + LSZ,
                                                       gcnb + DH, lng + DH, lnb + DH,
                                                       gfrag, gateb, nullptr, nullptr,
                                                       sc, j, offs, epk);
            // layer 2 + gate + tanh + RK4: gather hc28, node-local hc2 -> y (+y8)
            k_fused<true><<<NCHUNK, 256, 0, stream>>>(hc2, hc28, y, y8, wfrag + 2 * LSZ,
                                                      gcnb + 2 * DH, lng + 2 * DH, lnb + 2 * DH,
                                                      gfrag, gateb, hh, accg,
                                                      sc, j, offs, epk);
        }
    }

    k_outproj<<<GB1, 1024, 0, stream>>>(hh, wopk, bo, loutg, loutb, oacc);
    k_final<<<1, 128, 0, stream>>>(oacc, (float*)d_out);
}

// Round 12
// 6410.747 us; speedup vs baseline: 4.7296x; 1.1168x over previous
//
#include <hip/hip_runtime.h>

typedef unsigned int u32;
using bf16x8 = __attribute__((ext_vector_type(8))) short;
using f32x4  = __attribute__((ext_vector_type(4))) float;
using f32x2  = __attribute__((ext_vector_type(2))) float;

#define NN 20000
#define EE 320000
#define DH 128
#define DIN 64
#define TSTEPS 20
#define LNEPS 1e-5f
#define NCHUNK 1250   // 20000 / 16-node chunks; 1 block (4 waves) per chunk

// ---------- helpers ----------
__device__ __forceinline__ u32 f2bf(float f) {
    u32 x = __float_as_uint(f);
    return (x + 0x7fffu + ((x >> 16) & 1u)) >> 16;   // RNE to bf16 bits
}
__device__ __forceinline__ float bflo(u32 p) { return __uint_as_float(p << 16); }
__device__ __forceinline__ float bfhi(u32 p) { return __uint_as_float(p & 0xffff0000u); }
__device__ __forceinline__ u32 packbf(float a, float b) { return f2bf(a) | (f2bf(b) << 16); }
__device__ __forceinline__ float wredsum(float v) {
#pragma unroll
    for (int m = 32; m >= 1; m >>= 1) v += __shfl_xor(v, m, 64);
    return v;
}
__device__ __forceinline__ float sigm(float x) { return 1.f / (1.f + __expf(-x)); }

// decode 8 fp8(e4m3) + weighted accumulate
__device__ __forceinline__ void accum8_fp8(float* a, uint2 q, float w) {
    f32x2 c01 = __builtin_amdgcn_cvt_pk_f32_fp8((int)q.x, false);
    f32x2 c23 = __builtin_amdgcn_cvt_pk_f32_fp8((int)q.x, true);
    f32x2 c45 = __builtin_amdgcn_cvt_pk_f32_fp8((int)q.y, false);
    f32x2 c67 = __builtin_amdgcn_cvt_pk_f32_fp8((int)q.y, true);
    a[0] += w * c01[0]; a[1] += w * c01[1];
    a[2] += w * c23[0]; a[3] += w * c23[1];
    a[4] += w * c45[0]; a[5] += w * c45[1];
    a[6] += w * c67[0]; a[7] += w * c67[1];
}

// decode 8 consecutive fp8 -> bf16x8 A-frag (fp8 values are exact in bf16)
__device__ __forceinline__ bf16x8 dec8(uint2 pr) {
    f32x2 c01 = __builtin_amdgcn_cvt_pk_f32_fp8((int)pr.x, false);
    f32x2 c23 = __builtin_amdgcn_cvt_pk_f32_fp8((int)pr.x, true);
    f32x2 c45 = __builtin_amdgcn_cvt_pk_f32_fp8((int)pr.y, false);
    f32x2 c67 = __builtin_amdgcn_cvt_pk_f32_fp8((int)pr.y, true);
    union { u32 w[4]; bf16x8 v; } cv;
    cv.w[0] = packbf(c01[0], c01[1]);
    cv.w[1] = packbf(c23[0], c23[1]);
    cv.w[2] = packbf(c45[0], c45[1]);
    cv.w[3] = packbf(c67[0], c67[1]);
    return cv.v;
}

// single fp8 element at col from a 128-col fp8 row.
// NOTE: word-select of cvt_pk_f32_fp8 must be an immediate -> select between
// the two constant-imm variants (compiles to v_cndmask on the results).
__device__ __forceinline__ float fp8_at(const u32* row8, int col) {
    u32 w = row8[col >> 2];
    f32x2 dlo = __builtin_amdgcn_cvt_pk_f32_fp8((int)w, false);
    f32x2 dhi = __builtin_amdgcn_cvt_pk_f32_fp8((int)w, true);
    float e = (col & 2) ? ((col & 1) ? dhi[1] : dhi[0])
                        : ((col & 1) ? dlo[1] : dlo[0]);
    return e;
}

// fp8-only store (C/D layout: o at col=16j+sub); wave-uniform call site
__device__ __forceinline__ void store_fp8(u32* dst8, int node, int j, int sub, float o) {
    float po = __shfl_xor(o, 1, 64);
    int pk = __builtin_amdgcn_cvt_pk_fp8_f32(o, po, 0, false);
    int pk2 = __shfl_xor(pk, 2, 64);
    if (!(sub & 3)) dst8[node * 32 + j * 4 + (sub >> 2)] = (u32)(pk & 0xffff) | ((u32)pk2 << 16);
}

// dual store for y: bf16 row (residual path) + fp8 row (gather)
__device__ __forceinline__ void store_dual(u32* dstb, u32* dst8, int node, int j, int sub, float o) {
    float po = __shfl_xor(o, 1, 64);
    if (!(sub & 1)) dstb[node * 64 + j * 8 + (sub >> 1)] = packbf(o, po);
    int pk = __builtin_amdgcn_cvt_pk_fp8_f32(o, po, 0, false);
    int pk2 = __shfl_xor(pk, 2, 64);
    if (!(sub & 3)) dst8[node * 32 + j * 4 + (sub >> 2)] = (u32)(pk & 0xffff) | ((u32)pk2 << 16);
}

// ---------- setup kernels ----------
__global__ void k_init(int* deg, float* oacc) {
    int i = blockIdx.x * blockDim.x + threadIdx.x;
    if (i < NN) deg[i] = 0;
    if (i < DH) oacc[i] = 0.f;
}

__global__ void k_scalars(const float* meth, const float* hist, const float* logd,
                          const float* resw, float* sc) {
    float msum = 0.f;
    for (int j = 0; j < DH; j++) msum += sigm(meth[j]);
    float msil = msum * (1.f / DH);
    float h0 = sigm(hist[0]), h1 = sigm(hist[1]), h2 = sigm(hist[2]), h3 = sigm(hist[3]);
    float act = 0.5f * (h0 + h2), rep = 0.5f * (h1 + h3);
    float access = fminf(fmaxf(act - rep + 0.5f, 0.f), 1.f);
    sc[0] = access * (1.f - msil);
    float depth = fminf(fmaxf(__expf(logd[0]), 0.1f), 3.f);
    sc[1] = depth / (float)(TSTEPS - 1);
    sc[2] = resw[0];
}

__global__ void k_deg(const int* col, int* deg) {
    int e = blockIdx.x * blockDim.x + threadIdx.x;
    if (e < EE) atomicAdd(&deg[col[e]], 1);
}

__global__ __launch_bounds__(1024) void k_scan(const int* deg, int* offs, int* cursor, float* dis) {
    __shared__ int part[1024];
    const int CH = (NN + 1023) / 1024;
    int t = threadIdx.x;
    int base = t * CH;
    int s = 0;
    for (int k = 0; k < CH; k++) { int i = base + k; if (i < NN) s += deg[i]; }
    part[t] = s;
    __syncthreads();
    for (int off = 1; off < 1024; off <<= 1) {
        int v = part[t];
        int add = (t >= off) ? part[t - off] : 0;
        __syncthreads();
        part[t] = v + add;
        __syncthreads();
    }
    int run = part[t] - s;
    for (int k = 0; k < CH; k++) {
        int i = base + k;
        if (i < NN) {
            offs[i] = run; cursor[i] = run;
            int d = deg[i];
            run += d;
            dis[i] = (d > 0) ? rsqrtf((float)d) : 0.f;
        }
    }
    if (t == 1023) offs[NN] = run;
}

// edge record: (bf16 norm << 16) | src  (src < 20000 fits 16 bits)
__global__ void k_scatter(const int* row, const int* col, int* cursor, const float* dis,
                          u32* epk) {
    int e = blockIdx.x * blockDim.x + threadIdx.x;
    if (e < EE) {
        int c = col[e], r = row[e];
        int pos = atomicAdd(&cursor[c], 1);
        epk[pos] = (f2bf(dis[r] * dis[c]) << 16) | (u32)r;
    }
}

// ---------- fragment-order weight packing (known-good) ----------
__global__ void k_pack(const float* gcnw, const float* gatew, const float* Wo,
                       u32* wfrag, u32* gfrag, u32* wopk) {
    int tid = blockIdx.x * blockDim.x + threadIdx.x;
    if (tid < 6144) {                       // 3 layers * 4q * 8j * 64 lanes
        int lane = tid & 63, rem = tid >> 6;
        int j = rem & 7; rem >>= 3;
        int q = rem & 3; int l = rem >> 2;
        const float* W = gcnw + l * DH * DH;
        int r0 = 32 * q + 8 * (lane >> 4);
        int c  = 16 * j + (lane & 15);
        u32* o = wfrag + tid * 4;
#pragma unroll
        for (int p = 0; p < 4; p++)
            o[p] = packbf(W[(r0 + 2 * p) * DH + c], W[(r0 + 2 * p + 1) * DH + c]);
    } else if (tid < 6144 + 4096) {         // 8q * 8j * 64 lanes (gate 256x128)
        int t = tid - 6144;
        int lane = t & 63, rem = t >> 6;
        int j = rem & 7, q = rem >> 3;
        int r0 = 32 * q + 8 * (lane >> 4);
        int c  = 16 * j + (lane & 15);
        u32* o = gfrag + t * 4;
#pragma unroll
        for (int p = 0; p < 4; p++)
            o[p] = packbf(gatew[(r0 + 2 * p) * DH + c], gatew[(r0 + 2 * p + 1) * DH + c]);
    } else if (tid < 6144 + 4096 + 8192) {  // 64*128 u32 (Wo pair-packed)
        int t = tid - 10240;
        int k2 = t / DH, j = t % DH;
        wopk[t] = packbf(Wo[(2 * k2) * DH + j], Wo[(2 * k2 + 1) * DH + j]);
    }
}

// ---------- input projection: writes bf16 y, fp8 y8, fp32 hh ----------
__global__ __launch_bounds__(1024) void k_inproj(const float* x, const float* Wi, const float* bi,
                                                 const float* g, const float* b, const float* sc,
                                                 u32* y, u32* y8, float* hh) {
    __shared__ float Wl[DIN * DH];
    for (int i = threadIdx.x; i < DIN * DH; i += 1024) Wl[i] = Wi[i];
    __syncthreads();
    int wv = threadIdx.x >> 6, t = threadIdx.x & 63;
    int n = blockIdx.x * 16 + wv;
    if (n >= NN) return;
    float xv = x[n * DIN + t];
    float2 bb = *(const float2*)&bi[2 * t];
    float y0 = bb.x, y1 = bb.y;
#pragma unroll
    for (int k = 0; k < DIN; k++) {
        float a = __shfl(xv, k, 64);
        float2 w = *(const float2*)&Wl[k * DH + 2 * t];
        y0 += a * w.x; y1 += a * w.y;
    }
    float mu = wredsum(y0 + y1) * (1.f / DH);
    float d0 = y0 - mu, d1 = y1 - mu;
    float var = wredsum(d0 * d0 + d1 * d1) * (1.f / DH);
    float r = rsqrtf(var + LNEPS);
    float2 gg = *(const float2*)&g[2 * t], lb = *(const float2*)&b[2 * t];
    float scale = sc[0];
    float v0 = fmaxf(d0 * r * gg.x + lb.x, 0.f) * scale;
    float v1 = fmaxf(d1 * r * gg.y + lb.y, 0.f) * scale;
    y[n * 64 + t] = packbf(v0, v1);
    *(float2*)&hh[n * DH + 2 * t] = make_float2(v0, v1);
    int pk = __builtin_amdgcn_cvt_pk_fp8_f32(v0, v1, 0, false);
    int pk2 = __shfl_xor(pk, 1, 64);
    if (!(t & 1)) y8[n * 32 + (t >> 1)] = (u32)(pk & 0xffff) | ((u32)pk2 << 16);
}

// ---------- gather ONE row per quarter-wave, ALL 16 edge-loads in flight ----------
__device__ __forceinline__ void gather_row(const u32* __restrict__ src8, u32* tile,
                                           int row, int sub, int qb, int e0, int e1,
                                           const u32* __restrict__ epk) {
    float a[8] = {0.f, 0.f, 0.f, 0.f, 0.f, 0.f, 0.f, 0.f};
    for (int eb = e0; eb < e1; eb += 16) {
        int cc = min(16, e1 - eb);
        u32 p = 0;
        if (sub < cc) p = epk[eb + sub];
        u32 pe[16]; uint2 q[16];
#pragma unroll
        for (int u = 0; u < 16; u++) pe[u] = (u32)__shfl((int)p, qb + u, 64);
#pragma unroll
        for (int u = 0; u < 16; u++)
            q[u] = *(const uint2*)(src8 + (pe[u] & 0xffffu) * 32 + sub * 2);
#pragma unroll
        for (int u = 0; u < 16; u++)
            accum8_fp8(a, q[u], __uint_as_float(pe[u] & 0xffff0000u));
    }
    uint4 v;
    v.x = packbf(a[0], a[1]); v.y = packbf(a[2], a[3]);
    v.z = packbf(a[4], a[5]); v.w = packbf(a[6], a[7]);
    *(uint4*)(tile + row * 68 + sub * 4) = v;
}

// ---------- layer 0: gather + GEMM + LN -> fp8 only ----------
__global__ __launch_bounds__(256, 5) void k_aggmm(const u32* __restrict__ src8,
                                                  u32* __restrict__ dst8,
                                                  const u32* __restrict__ wfrag,
                                                  const float* __restrict__ bias,
                                                  const float* __restrict__ lng,
                                                  const float* __restrict__ lnb,
                                                  const int* __restrict__ offs,
                                                  const u32* __restrict__ epk) {
    __shared__ u32 tile[16 * 68];
    __shared__ float lred1[4][16], lred2[4][16];
    int wv = threadIdx.x >> 6, lane = threadIdx.x & 63;
    int base = blockIdx.x * 16;
    int t4 = lane >> 4, sub = lane & 15;
    int row = wv * 4 + t4;
    int e0 = offs[base + row], e1 = offs[base + row + 1];
    gather_row(src8, tile, row, sub, t4 * 16, e0, e1, epk);
    __syncthreads();

    // GEMM1: this wave's 2 output j's only
    f32x4 acc[2];
#pragma unroll
    for (int jl = 0; jl < 2; jl++) acc[jl] = (f32x4){0.f, 0.f, 0.f, 0.f};
#pragma unroll
    for (int q = 0; q < 4; q++) {
        bf16x8 A = *(const bf16x8*)(tile + sub * 68 + q * 16 + t4 * 4);
#pragma unroll
        for (int jl = 0; jl < 2; jl++) {
            int j = 2 * wv + jl;
            bf16x8 B = *(const bf16x8*)(wfrag + ((q * 8 + j) * 64 + lane) * 4);
            acc[jl] = __builtin_amdgcn_mfma_f32_16x16x32_bf16(A, B, acc[jl], 0, 0, 0);
        }
    }
    // bias + partial LN sums (32 cols per wave) -> LDS reduce
    float s1[4] = {0.f, 0.f, 0.f, 0.f}, s2[4] = {0.f, 0.f, 0.f, 0.f};
#pragma unroll
    for (int jl = 0; jl < 2; jl++) {
        float bb = bias[16 * (2 * wv + jl) + sub];
#pragma unroll
        for (int r = 0; r < 4; r++) {
            float v = acc[jl][r] + bb;
            acc[jl][r] = v;
            s1[r] += v; s2[r] += v * v;
        }
    }
#pragma unroll
    for (int r = 0; r < 4; r++) {
#pragma unroll
        for (int m = 1; m <= 8; m <<= 1) {
            s1[r] += __shfl_xor(s1[r], m, 64);
            s2[r] += __shfl_xor(s2[r], m, 64);
        }
        if (sub == 0) { lred1[wv][4 * t4 + r] = s1[r]; lred2[wv][4 * t4 + r] = s2[r]; }
    }
    __syncthreads();
    float mu[4], rs[4];
#pragma unroll
    for (int r = 0; r < 4; r++) {
        int n16 = 4 * t4 + r;
        float t1 = lred1[0][n16] + lred1[1][n16] + lred1[2][n16] + lred1[3][n16];
        float t2 = lred2[0][n16] + lred2[1][n16] + lred2[2][n16] + lred2[3][n16];
        mu[r] = t1 * (1.f / DH);
        float var = t2 * (1.f / DH) - mu[r] * mu[r];
        rs[r] = rsqrtf(var + LNEPS);
    }
#pragma unroll
    for (int jl = 0; jl < 2; jl++) {
        int j = 2 * wv + jl;
        float gg = lng[16 * j + sub], be = lnb[16 * j + sub];
#pragma unroll
        for (int r = 0; r < 4; r++) {
            float o = (acc[jl][r] - mu[r]) * rs[r] * gg + be;
            store_fp8(dst8, base + 4 * t4 + r, j, sub, o);
        }
    }
}

// ---------- fused: gather + GEMM + LN + gate GEMM + blend (+ RK4) ----------
// Intermediate state is fp8-only: src8 feeds gather, gate A-frags, and blend.
// yb (bf16) used only when LAST (residual read + RK4 state write).
template <bool LAST>
__global__ __launch_bounds__(256, 5) void k_fused(const u32* __restrict__ src8,
                                                  u32* __restrict__ yb,
                                                  u32* __restrict__ dst8,
                                                  const u32* __restrict__ wfragL,
                                                  const float* __restrict__ bias,
                                                  const float* __restrict__ lng,
                                                  const float* __restrict__ lnb,
                                                  const u32* __restrict__ gfrag,
                                                  const float* __restrict__ gateb,
                                                  float* __restrict__ hh,
                                                  unsigned short* __restrict__ acc_g,
                                                  const float* __restrict__ sc, int rkj,
                                                  const int* __restrict__ offs,
                                                  const u32* __restrict__ epk) {
    __shared__ u32 tile[16 * 68];
    __shared__ float lred1[4][16], lred2[4][16];
    int wv = threadIdx.x >> 6, lane = threadIdx.x & 63;
    int base = blockIdx.x * 16;
    int t4 = lane >> 4, sub = lane & 15;
    int row = wv * 4 + t4;
    int e0 = offs[base + row], e1 = offs[base + row + 1];

    // prefetch own-node A-frags from fp8 state (gate first half, exact in bf16)
    bf16x8 Ahc[4];
#pragma unroll
    for (int q = 0; q < 4; q++) {
        uint2 pr = *(const uint2*)(src8 + (base + sub) * 32 + q * 8 + t4 * 2);
        Ahc[q] = dec8(pr);
    }

    // LAST: prefetch cold epilogue operands (hh, residual row, RK4 acc)
    float hv_p[2][4]; u32 py_p[2][4]; float av_p[2][4];
    if (LAST) {
#pragma unroll
        for (int jl = 0; jl < 2; jl++) {
            int j = 2 * wv + jl;
#pragma unroll
            for (int r = 0; r < 4; r++) {
                int node = base + 4 * t4 + r;
                int fi = node * DH + 16 * j + sub;
                hv_p[jl][r] = hh[fi];
                py_p[jl][r] = yb[node * 64 + j * 8 + (sub >> 1)];
                av_p[jl][r] = (rkj != 0) ? __uint_as_float((u32)acc_g[fi] << 16) : 0.f;
            }
        }
    }

    gather_row(src8, tile, row, sub, t4 * 16, e0, e1, epk);
    __syncthreads();

    // GEMM1: this wave's 2 output j's only
    f32x4 acc[2];
#pragma unroll
    for (int jl = 0; jl < 2; jl++) acc[jl] = (f32x4){0.f, 0.f, 0.f, 0.f};
#pragma unroll
    for (int q = 0; q < 4; q++) {
        bf16x8 A = *(const bf16x8*)(tile + sub * 68 + q * 16 + t4 * 4);
#pragma unroll
        for (int jl = 0; jl < 2; jl++) {
            int j = 2 * wv + jl;
            bf16x8 B = *(const bf16x8*)(wfragL + ((q * 8 + j) * 64 + lane) * 4);
            acc[jl] = __builtin_amdgcn_mfma_f32_16x16x32_bf16(A, B, acc[jl], 0, 0, 0);
        }
    }

    // bias + partial LN sums -> LDS cross-wave reduce
    float s1[4] = {0.f, 0.f, 0.f, 0.f}, s2[4] = {0.f, 0.f, 0.f, 0.f};
#pragma unroll
    for (int jl = 0; jl < 2; jl++) {
        float bb = bias[16 * (2 * wv + jl) + sub];
#pragma unroll
        for (int r = 0; r < 4; r++) {
            float v = acc[jl][r] + bb;
            acc[jl][r] = v;
            s1[r] += v; s2[r] += v * v;
        }
    }
#pragma unroll
    for (int r = 0; r < 4; r++) {
#pragma unroll
        for (int m = 1; m <= 8; m <<= 1) {
            s1[r] += __shfl_xor(s1[r], m, 64);
            s2[r] += __shfl_xor(s2[r], m, 64);
        }
        if (sub == 0) { lred1[wv][4 * t4 + r] = s1[r]; lred2[wv][4 * t4 + r] = s2[r]; }
    }
    __syncthreads();   // also guarantees all GEMM1 tile reads done
    float mu[4], rs[4];
#pragma unroll
    for (int r = 0; r < 4; r++) {
        int n16 = 4 * t4 + r;
        float t1 = lred1[0][n16] + lred1[1][n16] + lred1[2][n16] + lred1[3][n16];
        float t2 = lred2[0][n16] + lred2[1][n16] + lred2[2][n16] + lred2[3][n16];
        mu[r] = t1 * (1.f / DH);
        float var = t2 * (1.f / DH) - mu[r] * mu[r];
        rs[r] = rsqrtf(var + LNEPS);
    }
#pragma unroll
    for (int jl = 0; jl < 2; jl++) {
        int j = 2 * wv + jl;
        float gg = lng[16 * j + sub], be = lnb[16 * j + sub];
#pragma unroll
        for (int r = 0; r < 4; r++)
            acc[jl][r] = (acc[jl][r] - mu[r]) * rs[r] * gg + be;
    }

    // hn -> tile (A-layout): each wave writes its own 32-col slice (disjoint)
#pragma unroll
    for (int jl = 0; jl < 2; jl++) {
        int j = 2 * wv + jl;
#pragma unroll
        for (int r = 0; r < 4; r++) {
            float o = acc[jl][r];
            float po = __shfl_xor(o, 1, 64);
            if (!(sub & 1)) tile[(4 * t4 + r) * 68 + j * 8 + (sub >> 1)] = packbf(o, po);
        }
    }
    __syncthreads();

    // GEMM2: gate logits (K=256), this wave's 2 j's; hn A-frags read from LDS
    f32x4 ag[2];
#pragma unroll
    for (int jl = 0; jl < 2; jl++) ag[jl] = (f32x4){0.f, 0.f, 0.f, 0.f};
#pragma unroll
    for (int q = 0; q < 8; q++) {
        bf16x8 A = (q < 4) ? Ahc[q]
                           : *(const bf16x8*)(tile + sub * 68 + (q - 4) * 16 + t4 * 4);
#pragma unroll
        for (int jl = 0; jl < 2; jl++) {
            int j = 2 * wv + jl;
            bf16x8 B = *(const bf16x8*)(gfrag + ((q * 8 + j) * 64 + lane) * 4);
            ag[jl] = __builtin_amdgcn_mfma_f32_16x16x32_bf16(A, B, ag[jl], 0, 0, 0);
        }
    }

    // epilogue for own j's; blend operand decoded from the same fp8 rows
    float dt = 0.f, rw = 0.f;
    if (LAST) { dt = sc[1]; rw = sc[2]; }
#pragma unroll
    for (int jl = 0; jl < 2; jl++) {
        int j = 2 * wv + jl;
        float gbj = gateb[16 * j + sub];
#pragma unroll
        for (int r = 0; r < 4; r++) {
            int node = base + 4 * t4 + r;
            float g = sigm(ag[jl][r] + gbj);
            float hcv = fp8_at(src8 + node * 32, 16 * j + sub);   // L1/L2-warm
            float o = g * acc[jl][r] + (1.f - g) * hcv;
            if (!LAST) {
                store_fp8(dst8, node, j, sub, o);
            } else {
                float z = fminf(fmaxf(o, -15.f), 15.f);
                float e = __expf(2.f * z);
                float th = (e - 1.f) / (e + 1.f);
                float yv = (sub & 1) ? bfhi(py_p[jl][r]) : bflo(py_p[jl][r]);
                float kk = th + rw * yv;
                float wj = dt * (1.f / 6.f) * ((rkj == 1 || rkj == 2) ? 2.f : 1.f);
                int fi = node * DH + 16 * j + sub;
                float av = wj * kk + av_p[jl][r];
                acc_g[fi] = (unsigned short)f2bf(av);
                float hv = hv_p[jl][r];
                if (rkj < 3) {
                    float c = (rkj == 2) ? dt : 0.5f * dt;
                    store_dual(yb, dst8, node, j, sub, hv + c * kk);
                } else {
                    float f = hv + av;
                    hh[fi] = f;
                    store_dual(yb, dst8, node, j, sub, f);
                }
            }
        }
    }
}

// ---------- output projection + LN + global mean (known-good) ----------
__global__ __launch_bounds__(1024) void k_outproj(const float* __restrict__ hh, const u32* wopk,
                                                  const float* bo, const float* g, const float* b,
                                                  float* oacc) {
    __shared__ u32 Wl[64 * DH];
    __shared__ float red[DH];
    for (int i = threadIdx.x; i < 64 * DH; i += 1024) Wl[i] = wopk[i];
    if (threadIdx.x < DH) red[threadIdx.x] = 0.f;
    __syncthreads();
    int wv = threadIdx.x >> 6, t = threadIdx.x & 63;
    int n = blockIdx.x * 16 + wv;
    if (n < NN) {
        float2 hv = *(const float2*)&hh[n * DH + 2 * t];
        float h0 = hv.x, h1 = hv.y;
        float2 bb = *(const float2*)&bo[2 * t];
        float y0 = bb.x, y1 = bb.y;
#pragma unroll
        for (int k2 = 0; k2 < 64; k2++) {
            float a0 = __shfl(h0, k2, 64), a1 = __shfl(h1, k2, 64);
            uint2 wq = *(const uint2*)&Wl[k2 * DH + 2 * t];
            y0 += a0 * bflo(wq.x) + a1 * bfhi(wq.x);
            y1 += a0 * bflo(wq.y) + a1 * bfhi(wq.y);
        }
        float mu = wredsum(y0 + y1) * (1.f / DH);
        float d0 = y0 - mu, d1 = y1 - mu;
        float var = wredsum(d0 * d0 + d1 * d1) * (1.f / DH);
        float r = rsqrtf(var + LNEPS);
        float2 gg = *(const float2*)&g[2 * t], lb = *(const float2*)&b[2 * t];
        atomicAdd(&red[2 * t], d0 * r * gg.x + lb.x);
        atomicAdd(&red[2 * t + 1], d1 * r * gg.y + lb.y);
    }
    __syncthreads();
    if (threadIdx.x < DH) atomicAdd(&oacc[threadIdx.x], red[threadIdx.x]);
}

__global__ void k_final(const float* oacc, float* out) {
    int t = threadIdx.x;
    if (t < DH) out[t] = oacc[t] * (1.f / (float)NN);
}

// ---------- host ----------
extern "C" void kernel_launch(void* const* d_in, const int* in_sizes, int n_in,
                              void* d_out, int out_size, void* d_ws, size_t ws_size,
                              hipStream_t stream) {
    const float* x     = (const float*)d_in[0];
    const int*   ei    = (const int*)d_in[1];
    const float* Wi    = (const float*)d_in[2];
    const float* bi    = (const float*)d_in[3];
    const float* ling  = (const float*)d_in[4];
    const float* linb  = (const float*)d_in[5];
    const float* meth  = (const float*)d_in[6];
    const float* hist  = (const float*)d_in[7];
    const float* gcnw  = (const float*)d_in[8];
    const float* gcnb  = (const float*)d_in[9];
    const float* lng   = (const float*)d_in[10];
    const float* lnb   = (const float*)d_in[11];
    const float* gatew = (const float*)d_in[12];
    const float* gateb = (const float*)d_in[13];
    const float* resw  = (const float*)d_in[14];
    const float* logd  = (const float*)d_in[15];
    const float* Wo    = (const float*)d_in[16];
    const float* bo    = (const float*)d_in[17];
    const float* loutg = (const float*)d_in[18];
    const float* loutb = (const float*)d_in[19];

    char* wsb = (char*)d_ws;
    size_t off = 0;
    auto alloc = [&](size_t bytes) -> void* {
        void* p = wsb + off;
        off += (bytes + 255) & ~(size_t)255;
        return p;
    };
    float* sc     = (float*)alloc(32);
    int*   deg    = (int*)alloc(NN * 4);
    int*   offs   = (int*)alloc((NN + 1) * 4);
    int*   cursor = (int*)alloc(NN * 4);
    float* dis    = (float*)alloc(NN * 4);
    u32*   epk    = (u32*)alloc(EE * 4);
    u32*   wfrag  = (u32*)alloc(3 * 32 * 64 * 4 * 4);
    u32*   gfrag  = (u32*)alloc(64 * 64 * 4 * 4);
    u32*   wopk   = (u32*)alloc(64 * DH * 4);
    u32*   y      = (u32*)alloc((size_t)NN * 64 * 4);   // bf16 rows (residual path)
    u32*   y8     = (u32*)alloc((size_t)NN * 32 * 4);   // fp8 state rows
    u32*   hc8    = (u32*)alloc((size_t)NN * 32 * 4);
    u32*   hc28   = (u32*)alloc((size_t)NN * 32 * 4);
    float* hh     = (float*)alloc((size_t)NN * DH * 4);
    unsigned short* accg = (unsigned short*)alloc((size_t)NN * DH * 2);
    float* oacc   = (float*)alloc(DH * 4);

    const int* row = ei;
    const int* col = ei + EE;

    k_init<<<(NN + 255) / 256, 256, 0, stream>>>(deg, oacc);
    k_scalars<<<1, 1, 0, stream>>>(meth, hist, logd, resw, sc);
    k_deg<<<(EE + 255) / 256, 256, 0, stream>>>(col, deg);
    k_scan<<<1, 1024, 0, stream>>>(deg, offs, cursor, dis);
    k_scatter<<<(EE + 255) / 256, 256, 0, stream>>>(row, col, cursor, dis, epk);
    k_pack<<<(6144 + 4096 + 8192 + 255) / 256, 256, 0, stream>>>(gcnw, gatew, Wo, wfrag, gfrag, wopk);

    const int GB1 = (NN + 15) / 16;
    k_inproj<<<GB1, 1024, 0, stream>>>(x, Wi, bi, ling, linb, sc, y, y8, hh);

    const int LSZ = 32 * 64 * 4;      // u32 per layer of wfrag
    for (int s = 0; s < TSTEPS - 1; s++) {
        for (int j = 0; j < 4; j++) {
            // layer 0: gather y8 -> hc8 (fp8 only)
            k_aggmm<<<NCHUNK, 256, 0, stream>>>(y8, hc8, wfrag, gcnb, lng, lnb, offs, epk);
            // layer 1 + gate: gather hc8 -> hc28 (fp8 only)
            k_fused<false><<<NCHUNK, 256, 0, stream>>>(hc8, y, hc28, wfrag + LSZ,
                                                       gcnb + DH, lng + DH, lnb + DH,
                                                       gfrag, gateb, nullptr, nullptr,
                                                       sc, j, offs, epk);
            // layer 2 + gate + tanh + RK4: gather hc28 -> y (bf16) + y8 (fp8)
            k_fused<true><<<NCHUNK, 256, 0, stream>>>(hc28, y, y8, wfrag + 2 * LSZ,
                                                      gcnb + 2 * DH, lng + 2 * DH, lnb + 2 * DH,
                                                      gfrag, gateb, hh, accg,
                                                      sc, j, offs, epk);
        }
    }

    k_outproj<<<GB1, 1024, 0, stream>>>(hh, wopk, bo, loutg, loutb, oacc);
    k_final<<<1, 128, 0, stream>>>(oacc, (float*)d_out);
}